// Round 12
// baseline (348.901 us; speedup 1.0000x reference)
//
#include <hip/hip_runtime.h>
#include <cmath>

#define NTOK 3072
#define NBLK 3
#define PSS 133   // ps LDS stride: %32 == 5 -> conflict-free reads

__device__ __forceinline__ float sig(float v) { return 1.0f / (1.0f + expf(-v)); }

struct Params {
    const float *ql, *cl, *plm;
    const float *ada_g_w, *ada_g_b, *ada_b_w;
    const float *wq, *bq, *wk, *wv;
    const float *z_ln_g, *z_ln_b, *wz;
    const float *wg, *wo, *sg_w, *sg_b;
    const float *ada2_g_w, *ada2_g_b, *ada2_b_w;
    const float *ff1, *ff2, *ff3, *sg2_w, *sg2_b;
    float *qkvg, *ffb, *zb, *G;
    float *anew0, *anew1;
    float *out;
};

// 32-lane-subgroup row LN of 4 register values (cols (lane&31)*4 .. +3 of a 128-col row)
__device__ __forceinline__ float4 ln_row32(float4 v)
{
    float s = v.x + v.y + v.z + v.w;
#pragma unroll
    for (int m = 1; m < 32; m <<= 1) s += __shfl_xor(s, m);
    float mean = s * (1.0f / 128.0f);
    float d0 = v.x - mean, d1 = v.y - mean, d2 = v.z - mean, d3 = v.w - mean;
    float var = d0 * d0 + d1 * d1 + d2 * d2 + d3 * d3;
#pragma unroll
    for (int m = 1; m < 32; m <<= 1) var += __shfl_xor(var, m);
    float rs = 1.0f / sqrtf(var * (1.0f / 128.0f) + 1e-5f);
    return make_float4(d0 * rs, d1 * rs, d2 * rs, d3 * rs);
}

// ================= k0: all conditioning GEMMs (18 units) =================
// grid 1728 = 8 XCD x 12 tiles(32 rows) x 18 units (6 kinds x 3 layers)
__global__ __launch_bounds__(256) void k0_cond(Params P)
{
    __shared__ __align__(16) float smA[32 * 132];
    int tid = threadIdx.x, bid = blockIdx.x;
    const size_t NC = (size_t)NTOK * 128;
    int x8 = bid & 7, rest = bid >> 3;          // rest 0..215
    int tl = rest % 12, unit = rest / 12;       // unit 0..17
    int kind = unit % 6, i = unit / 6;
    int row0 = (x8 * 12 + tl) * 32;
#pragma unroll
    for (int it = 0; it < 4; it++) {
        int fo = (tid + it * 256) * 4, r = fo >> 7, c = fo & 127;
        *(float4*)&smA[r * 132 + c] = *(const float4*)&P.cl[(size_t)(row0 + r) * 128 + c];
    }
    __syncthreads();
    int hw = tid >> 5, cq = (tid & 31) * 4;
#pragma unroll
    for (int rr = 0; rr < 4; rr++) {
        int r = hw * 4 + rr;
        float4 n = ln_row32(*(float4*)&smA[r * 132 + cq]);
        *(float4*)&smA[r * 132 + cq] = n;
    }
    __syncthreads();
    const float* W; const float* bias = nullptr; bool dosig = false;
    switch (kind) {
        case 0:  W = P.ada_g_w  + (size_t)i * 16384; bias = P.ada_g_b  + i * 128; dosig = true; break;
        case 1:  W = P.ada_b_w  + (size_t)i * 16384; break;
        case 2:  W = P.ada2_g_w + (size_t)i * 16384; bias = P.ada2_g_b + i * 128; dosig = true; break;
        case 3:  W = P.ada2_b_w + (size_t)i * 16384; break;
        case 4:  W = P.sg_w     + (size_t)i * 16384; bias = P.sg_b     + i * 128; dosig = true; break;
        default: W = P.sg2_w    + (size_t)i * 16384; bias = P.sg2_b    + i * 128; dosig = true; break;
    }
    W += cq;
    float acc[4][4] = {};
#pragma unroll 8
    for (int k = 0; k < 128; k++) {
        float4 w4 = *(const float4*)(W + (size_t)k * 128);
#pragma unroll
        for (int rr = 0; rr < 4; rr++) {
            float a = smA[(hw * 4 + rr) * 132 + k];
            acc[rr][0] = fmaf(a, w4.x, acc[rr][0]);
            acc[rr][1] = fmaf(a, w4.y, acc[rr][1]);
            acc[rr][2] = fmaf(a, w4.z, acc[rr][2]);
            acc[rr][3] = fmaf(a, w4.w, acc[rr][3]);
        }
    }
    float4 b4 = bias ? *(const float4*)&bias[cq] : make_float4(0, 0, 0, 0);
    float* dst = P.G + (size_t)(kind * NBLK + i) * NC;
#pragma unroll
    for (int rr = 0; rr < 4; rr++) {
        float4 o = make_float4(acc[rr][0] + b4.x, acc[rr][1] + b4.y,
                               acc[rr][2] + b4.z, acc[rr][3] + b4.w);
        if (dosig) { o.x = sig(o.x); o.y = sig(o.y); o.z = sig(o.z); o.w = sig(o.w); }
        *(float4*)&dst[(size_t)(row0 + hw * 4 + rr) * 128 + cq] = o;
    }
}

// ================= kA: x|y elementwise + single projection GEMM ==========
// blocks 0..575: 8 XCD x 12 tiles(32 rows) x 6 units {q,k,v,g, ff-lo, ff-hi}
//   u==0 blocks also zero-fill `dest` (the buffer kB(i) will atomically accumulate).
// i==0 only: blocks 576..959 compute zb (8 XCD x 12 j x 4 kk-chunks).
__global__ __launch_bounds__(256) void kA_pre(Params P, int i,
                                              const float* __restrict__ aprev,
                                              float* __restrict__ dest)
{
    __shared__ __align__(16) float smX[32 * 132];
    __shared__ __align__(16) float wzg[204];
    const size_t NC = (size_t)NTOK * 128;
    int tid = threadIdx.x, bid = blockIdx.x;
    if (bid < 576) {
        int x8 = bid & 7, rest = bid >> 3;      // 0..71
        int tl = rest % 12, u = rest / 12;      // u 0..5
        int row0 = (x8 * 12 + tl) * 32;
        int hw = tid >> 5, cq = (tid & 31) * 4;
        if (u == 0) {
            // zero-fill destination rows for kB's atomic accumulation
            float4 z4 = make_float4(0, 0, 0, 0);
#pragma unroll
            for (int it = 0; it < 4; it++) {
                int fo = (tid + it * 256) * 4, r = fo >> 7, c = fo & 127;
                *(float4*)&dest[(size_t)(row0 + r) * 128 + c] = z4;
            }
        }
        const float* Gg = P.G + (size_t)(((u < 4 ? 0 : 2) * NBLK) + i) * NC;
        const float* Gb = P.G + (size_t)(((u < 4 ? 1 : 3) * NBLK) + i) * NC;
#pragma unroll
        for (int rr = 0; rr < 4; rr++) {
            int r = row0 + hw * 4 + rr;
            float4 a4 = *(const float4*)&aprev[(size_t)r * 128 + cq];
            float4 ln4 = ln_row32(a4);
            float4 g4 = *(const float4*)&Gg[(size_t)r * 128 + cq];
            float4 b4 = *(const float4*)&Gb[(size_t)r * 128 + cq];
            float4 x4;
            x4.x = fmaf(g4.x, ln4.x, b4.x);
            x4.y = fmaf(g4.y, ln4.y, b4.y);
            x4.z = fmaf(g4.z, ln4.z, b4.z);
            x4.w = fmaf(g4.w, ln4.w, b4.w);
            *(float4*)&smX[(hw * 4 + rr) * 132 + cq] = x4;
        }
        __syncthreads();
        if (u < 4) {
            const float* W = (u == 0 ? P.wq : u == 1 ? P.wk : u == 2 ? P.wv : P.wg)
                             + (size_t)i * 16384 + cq;
            float acc[4][4] = {};
#pragma unroll 8
            for (int k = 0; k < 128; k++) {
                float4 w4 = *(const float4*)(W + (size_t)k * 128);
#pragma unroll
                for (int rr = 0; rr < 4; rr++) {
                    float a = smX[(hw * 4 + rr) * 132 + k];
                    acc[rr][0] = fmaf(a, w4.x, acc[rr][0]);
                    acc[rr][1] = fmaf(a, w4.y, acc[rr][1]);
                    acc[rr][2] = fmaf(a, w4.z, acc[rr][2]);
                    acc[rr][3] = fmaf(a, w4.w, acc[rr][3]);
                }
            }
            float4 b4 = (u == 0) ? *(const float4*)&P.bq[(size_t)i * 128 + cq]
                                 : make_float4(0, 0, 0, 0);
#pragma unroll
            for (int rr = 0; rr < 4; rr++) {
                int r = row0 + hw * 4 + rr;
                *(float4*)&P.qkvg[(size_t)r * 512 + u * 128 + cq] =
                    make_float4(acc[rr][0] + b4.x, acc[rr][1] + b4.y,
                                acc[rr][2] + b4.z, acc[rr][3] + b4.w);
            }
        } else {
            int ch = (u - 4) * 128;
            const float* W1 = P.ff1 + (size_t)i * 32768 + ch + cq;
            const float* W2 = P.ff2 + (size_t)i * 32768 + ch + cq;
            float a1[4][4] = {}, a2[4][4] = {};
#pragma unroll 4
            for (int k = 0; k < 128; k++) {
                float4 w14 = *(const float4*)(W1 + (size_t)k * 256);
                float4 w24 = *(const float4*)(W2 + (size_t)k * 256);
#pragma unroll
                for (int rr = 0; rr < 4; rr++) {
                    float a = smX[(hw * 4 + rr) * 132 + k];
                    a1[rr][0] = fmaf(a, w14.x, a1[rr][0]);
                    a1[rr][1] = fmaf(a, w14.y, a1[rr][1]);
                    a1[rr][2] = fmaf(a, w14.z, a1[rr][2]);
                    a1[rr][3] = fmaf(a, w14.w, a1[rr][3]);
                    a2[rr][0] = fmaf(a, w24.x, a2[rr][0]);
                    a2[rr][1] = fmaf(a, w24.y, a2[rr][1]);
                    a2[rr][2] = fmaf(a, w24.z, a2[rr][2]);
                    a2[rr][3] = fmaf(a, w24.w, a2[rr][3]);
                }
            }
#pragma unroll
            for (int rr = 0; rr < 4; rr++) {
                int r = row0 + hw * 4 + rr;
                float4 o;
                o.x = a1[rr][0] * sig(a1[rr][0]) * a2[rr][0];
                o.y = a1[rr][1] * sig(a1[rr][1]) * a2[rr][1];
                o.z = a1[rr][2] * sig(a1[rr][2]) * a2[rr][2];
                o.w = a1[rr][3] * sig(a1[rr][3]) * a2[rr][3];
                *(float4*)&P.ffb[(size_t)r * 256 + ch + cq] = o;
            }
        }
    } else {
        // zb: only launched at i==0. blocks 576..959
        int b2 = bid - 576;
        int x8 = b2 & 7, rest = b2 >> 3;    // rest 0..47
        int jl = rest >> 2, kkc = rest & 3;
        int j = x8 * 12 + jl;
        if (tid < 192) {
            int i3 = tid >> 6, rem = tid & 63, c = rem >> 2, h = rem & 3;
            wzg[(i3 * 16 + c) * 4 + h] = P.z_ln_g[i3 * 16 + c] * P.wz[(i3 * 16 + c) * 4 + h];
        }
        if (tid < 12) {
            int i3 = tid >> 2, h = tid & 3;
            float s = 0.0f;
            for (int c = 0; c < 16; c++) s += P.z_ln_b[i3 * 16 + c] * P.wz[(i3 * 16 + c) * 4 + h];
            wzg[192 + tid] = s;
        }
        __syncthreads();
        int kstart = max(0, j * 32 - 48);
        int W = min(NTOK, j * 32 + 80) - kstart;
#pragma unroll
        for (int it = 0; it < 4; it++) {
            int idx = tid + it * 256;
            int qi = idx >> 5, kk = kkc * 32 + (idx & 31);
            if (kk >= W) continue;
            int q = j * 32 + qi;
            const float* src = P.plm + ((size_t)q * NTOK + (size_t)(kstart + kk)) * 16;
            float xv[16];
            *(float4*)(xv + 0)  = *(const float4*)(src + 0);
            *(float4*)(xv + 4)  = *(const float4*)(src + 4);
            *(float4*)(xv + 8)  = *(const float4*)(src + 8);
            *(float4*)(xv + 12) = *(const float4*)(src + 12);
            float s = 0.0f;
#pragma unroll
            for (int c = 0; c < 16; c++) s += xv[c];
            float mean = s * (1.0f / 16.0f);
            float var = 0.0f;
#pragma unroll
            for (int c = 0; c < 16; c++) { float d = xv[c] - mean; var += d * d; }
            float rs = 1.0f / sqrtf(var * (1.0f / 16.0f) + 1e-5f);
#pragma unroll
            for (int c = 0; c < 16; c++) xv[c] = (xv[c] - mean) * rs;
#pragma unroll
            for (int i3 = 0; i3 < NBLK; i3++) {
#pragma unroll
                for (int h = 0; h < 4; h++) {
                    float o = wzg[192 + i3 * 4 + h];
#pragma unroll
                    for (int c = 0; c < 16; c++) o = fmaf(xv[c], wzg[(i3 * 16 + c) * 4 + h], o);
                    P.zb[((size_t)(i3 * 4 + h) * NTOK + q) * 128 + kk] = o;
                }
            }
        }
    }
}

// ================= kB: attention + per-head wo partial -> atomicAdd dest (blocks 0..767)
//                      + tpart = sig(sg2)·(ffb@ff3) -> atomicAdd dest  (blocks 768..1151) ====
__global__ __launch_bounds__(256) void kB_attn(Params P, int i, float* __restrict__ dest)
{
    __shared__ __align__(16) float sm[11344];   // ks[4608] | vs[4608] | ps[16*133]; union tpart [16*260]
    const size_t NC = (size_t)NTOK * 128;
    int tid = threadIdx.x, bid = blockIdx.x;
    if (bid < 768) {
        float* ks = sm;             // [128][36]; reused as o_s[16][33] after QK^T/PV
        float* vs = sm + 4608;      // [128][36]
        float* ps = sm + 9216;      // [16][PSS]
        int x8 = bid & 7, g = bid >> 3;            // 0..95
        int jl = g >> 3, rem = g & 7;
        int h = rem >> 1, qh = rem & 1;
        int jglob = x8 * 12 + jl;
        int q0 = jglob * 32 + qh * 16;
        int kstart = max(0, jglob * 32 - 48);
        int W = min(NTOK, jglob * 32 + 80) - kstart;
        for (int idx = tid; idx < W * 8; idx += 256) {
            int kk = idx >> 3, d = (idx & 7) * 4;
            const float* base = &P.qkvg[(size_t)(kstart + kk) * 512 + 128 + h * 32 + d];
            float4 tK = *(const float4*)base;
            float4 tV = *(const float4*)(base + 128);
            *(float4*)&ks[kk * 36 + d] = tK;
            *(float4*)&vs[kk * 36 + d] = tV;
        }
        const float* zbase = &P.zb[((size_t)(i * 4 + h) * NTOK + q0) * 128];
#pragma unroll
        for (int it = 0; it < 2; it++) {
            int idx = tid + it * 256;
            int r = idx >> 5, c4 = (idx & 31) * 4;
            float4 z4 = *(const float4*)&zbase[(size_t)r * 128 + c4];
            ps[r * PSS + c4]     = z4.x;
            ps[r * PSS + c4 + 1] = z4.y;
            ps[r * PSS + c4 + 2] = z4.z;
            ps[r * PSS + c4 + 3] = z4.w;
        }
        int qi = tid & 15, kg = tid >> 4;
        float qreg[32];
        {
            const float* qp = &P.qkvg[(size_t)(q0 + qi) * 512 + h * 32];
#pragma unroll
            for (int d4 = 0; d4 < 8; d4++) {
                float4 tq = *(const float4*)(qp + d4 * 4);
                qreg[d4 * 4] = tq.x; qreg[d4 * 4 + 1] = tq.y;
                qreg[d4 * 4 + 2] = tq.z; qreg[d4 * 4 + 3] = tq.w;
            }
        }
        __syncthreads();
        const float scale = 0.17677669529663687f;  // 1/sqrt(32)
#pragma unroll
        for (int t2 = 0; t2 < 8; t2++) {
            int kk = kg + t2 * 16;
            if (kk < W) {
                float acc = 0.0f;
#pragma unroll
                for (int d4 = 0; d4 < 8; d4++) {
                    float4 kv = *(const float4*)&ks[kk * 36 + d4 * 4];
                    acc = fmaf(qreg[d4 * 4 + 0], kv.x, acc);
                    acc = fmaf(qreg[d4 * 4 + 1], kv.y, acc);
                    acc = fmaf(qreg[d4 * 4 + 2], kv.z, acc);
                    acc = fmaf(qreg[d4 * 4 + 3], kv.w, acc);
                }
                ps[qi * PSS + kk] = fmaf(acc, scale, ps[qi * PSS + kk]);
            }
        }
        __syncthreads();
        {
            int row = tid >> 4, sub = tid & 15;
            float m = -3.0e38f;
            for (int kk = sub; kk < W; kk += 16) m = fmaxf(m, ps[row * PSS + kk]);
#pragma unroll
            for (int s2 = 1; s2 < 16; s2 <<= 1) m = fmaxf(m, __shfl_xor(m, s2));
            float ssum = 0.0f;
            for (int kk = sub; kk < W; kk += 16) {
                float e = expf(ps[row * PSS + kk] - m);
                ps[row * PSS + kk] = e; ssum += e;
            }
#pragma unroll
            for (int s2 = 1; s2 < 16; s2 <<= 1) ssum += __shfl_xor(ssum, s2);
            float rinv = 1.0f / ssum;
            for (int kk = sub; kk < W; kk += 16) ps[row * PSS + kk] *= rinv;
        }
        __syncthreads();
        {
            int dg = tid >> 4, d0 = dg * 2;
            float o0 = 0.0f, o1 = 0.0f, o0b = 0.0f, o1b = 0.0f;
            for (int kk = 0; kk + 1 < W; kk += 2) {
                float p0 = ps[qi * PSS + kk], p1 = ps[qi * PSS + kk + 1];
                float2 va = *(const float2*)&vs[kk * 36 + d0];
                float2 vb = *(const float2*)&vs[(kk + 1) * 36 + d0];
                o0  = fmaf(p0, va.x, o0);  o1  = fmaf(p0, va.y, o1);
                o0b = fmaf(p1, vb.x, o0b); o1b = fmaf(p1, vb.y, o1b);
            }
            if (W & 1) {
                float p0 = ps[qi * PSS + W - 1];
                float2 va = *(const float2*)&vs[(W - 1) * 36 + d0];
                o0 = fmaf(p0, va.x, o0); o1 = fmaf(p0, va.y, o1);
            }
            o0 += o0b; o1 += o1b;
            float2 g2 = *(const float2*)&P.qkvg[(size_t)(q0 + qi) * 512 + 384 + h * 32 + d0];
            // g-gated head output -> LDS (ks region is dead after QK^T)
            ks[qi * 33 + d0]     = o0 * sig(g2.x);
            ks[qi * 33 + d0 + 1] = o1 * sig(g2.y);
        }
        __syncthreads();
        // per-head wo partial, gated by sig(sg), atomically accumulated into dest
        {
            int r = tid >> 4, ci = tid & 15;
            int c0 = ci * 8;
            const float* o_s = ks;
            const float* wop = P.wo + (size_t)i * 16384 + (size_t)(h * 32) * 128 + c0;
            float acc[8] = {};
#pragma unroll 4
            for (int d = 0; d < 32; d++) {
                float a = o_s[r * 33 + d];
                float4 w0 = *(const float4*)(wop + (size_t)d * 128);
                float4 w1 = *(const float4*)(wop + (size_t)d * 128 + 4);
                acc[0] = fmaf(a, w0.x, acc[0]); acc[1] = fmaf(a, w0.y, acc[1]);
                acc[2] = fmaf(a, w0.z, acc[2]); acc[3] = fmaf(a, w0.w, acc[3]);
                acc[4] = fmaf(a, w1.x, acc[4]); acc[5] = fmaf(a, w1.y, acc[5]);
                acc[6] = fmaf(a, w1.z, acc[6]); acc[7] = fmaf(a, w1.w, acc[7]);
            }
            size_t off = (size_t)(q0 + r) * 128 + c0;
            const float* gsrow = &P.G[(size_t)(4 * NBLK + i) * NC + off];
            float4 gs0 = *(const float4*)gsrow;
            float4 gs1 = *(const float4*)(gsrow + 4);
            float* dst = dest + off;
            atomicAdd(dst + 0, gs0.x * acc[0]);
            atomicAdd(dst + 1, gs0.y * acc[1]);
            atomicAdd(dst + 2, gs0.z * acc[2]);
            atomicAdd(dst + 3, gs0.w * acc[3]);
            atomicAdd(dst + 4, gs1.x * acc[4]);
            atomicAdd(dst + 5, gs1.y * acc[5]);
            atomicAdd(dst + 6, gs1.z * acc[6]);
            atomicAdd(dst + 7, gs1.w * acc[7]);
        }
    } else {
        // tpart = sig(sg2)·(ffb @ ff3): 384 blocks = 8 XCD x 24 tiles(16r) x 2 col-halves(64)
        float* smC = sm;   // [16][260]
        int b2 = bid - 768;
        int x8 = b2 & 7, rest = b2 >> 3;    // 0..47
        int tl = rest >> 1, chalf = rest & 1;
        int row0 = x8 * 384 + tl * 16;
#pragma unroll
        for (int it = 0; it < 4; it++) {
            int fo = (tid + it * 256) * 4, r = fo >> 8, c = fo & 255;
            *(float4*)&smC[r * 260 + c] = *(const float4*)&P.ffb[(size_t)(row0 + r) * 256 + c];
        }
        __syncthreads();
        int r = tid >> 4, c = chalf * 64 + (tid & 15) * 4;
        const float* f3_p = P.ff3 + (size_t)i * 32768 + c;
        float acc[4] = {};
#pragma unroll 8
        for (int k = 0; k < 256; k++) {
            float4 w4 = *(const float4*)(f3_p + (size_t)k * 128);
            float a = smC[r * 260 + k];
            acc[0] = fmaf(a, w4.x, acc[0]);
            acc[1] = fmaf(a, w4.y, acc[1]);
            acc[2] = fmaf(a, w4.z, acc[2]);
            acc[3] = fmaf(a, w4.w, acc[3]);
        }
        int row = row0 + r;
        size_t off = (size_t)row * 128 + c;
        float4 g5 = *(const float4*)&P.G[(size_t)(5 * NBLK + i) * NC + off];
        float* dst = dest + off;
        atomicAdd(dst + 0, g5.x * acc[0]);
        atomicAdd(dst + 1, g5.y * acc[1]);
        atomicAdd(dst + 2, g5.z * acc[2]);
        atomicAdd(dst + 3, g5.w * acc[3]);
    }
}

extern "C" void kernel_launch(void* const* d_in, const int* in_sizes, int n_in,
                              void* d_out, int out_size, void* d_ws, size_t ws_size,
                              hipStream_t stream)
{
    Params P;
    P.ql       = (const float*)d_in[0];
    P.cl       = (const float*)d_in[1];
    P.plm      = (const float*)d_in[2];
    P.ada_g_w  = (const float*)d_in[3];
    P.ada_g_b  = (const float*)d_in[4];
    P.ada_b_w  = (const float*)d_in[5];
    P.wq       = (const float*)d_in[6];
    P.bq       = (const float*)d_in[7];
    P.wk       = (const float*)d_in[8];
    P.wv       = (const float*)d_in[9];
    P.z_ln_g   = (const float*)d_in[10];
    P.z_ln_b   = (const float*)d_in[11];
    P.wz       = (const float*)d_in[12];
    P.wg       = (const float*)d_in[13];
    P.wo       = (const float*)d_in[14];
    P.sg_w     = (const float*)d_in[15];
    P.sg_b     = (const float*)d_in[16];
    P.ada2_g_w = (const float*)d_in[17];
    P.ada2_g_b = (const float*)d_in[18];
    P.ada2_b_w = (const float*)d_in[19];
    P.ff1      = (const float*)d_in[20];
    P.ff2      = (const float*)d_in[21];
    P.ff3      = (const float*)d_in[22];
    P.sg2_w    = (const float*)d_in[23];
    P.sg2_b    = (const float*)d_in[24];

    float* ws = (float*)d_ws;
    const size_t NC = (size_t)NTOK * 128;
    P.qkvg  = ws;             // N x 512
    P.ffb   = ws + 4 * NC;    // N x 256
    P.zb    = ws + 6 * NC;    // 3 x 4 x N x 128
    P.G     = ws + 18 * NC;   // 18 x N x 128 (6 kinds x 3 layers)
    P.anew0 = ws + 36 * NC;   // N x 128
    P.anew1 = ws + 37 * NC;   // N x 128
    P.out   = (float*)d_out;

    const float* aprev[NBLK] = { P.ql, P.anew0, P.anew1 };
    float*       dest [NBLK] = { P.anew0, P.anew1, P.out };

    k0_cond<<<1728, 256, 0, stream>>>(P);
    for (int i = 0; i < NBLK; i++) {
        kA_pre<<<(i == 0 ? 960 : 576), 256, 0, stream>>>(P, i, aprev[i], dest[i]);
        kB_attn<<<1152, 256, 0, stream>>>(P, i, dest[i]);
    }
}

// Round 13
// 278.425 us; speedup vs baseline: 1.2531x; 1.2531x over previous
//
#include <hip/hip_runtime.h>
#include <cmath>

#define NTOK 3072
#define NBLK 3
#define PSS 133   // ps LDS stride: %32 == 5 -> conflict-free reads

__device__ __forceinline__ float sig(float v) { return 1.0f / (1.0f + expf(-v)); }

struct Params {
    const float *ql, *cl, *plm;
    const float *ada_g_w, *ada_g_b, *ada_b_w;
    const float *wq, *bq, *wk, *wv;
    const float *z_ln_g, *z_ln_b, *wz;
    const float *wg, *wo, *sg_w, *sg_b;
    const float *ada2_g_w, *ada2_g_b, *ada2_b_w;
    const float *ff1, *ff2, *ff3, *sg2_w, *sg2_b;
    float *qkvg, *ffb, *zb, *G, *bout4, *tpart;
    float *out;
};

// 32-lane-subgroup row LN of 4 register values (cols (lane&31)*4 .. +3 of a 128-col row)
__device__ __forceinline__ float4 ln_row32(float4 v)
{
    float s = v.x + v.y + v.z + v.w;
#pragma unroll
    for (int m = 1; m < 32; m <<= 1) s += __shfl_xor(s, m);
    float mean = s * (1.0f / 128.0f);
    float d0 = v.x - mean, d1 = v.y - mean, d2 = v.z - mean, d3 = v.w - mean;
    float var = d0 * d0 + d1 * d1 + d2 * d2 + d3 * d3;
#pragma unroll
    for (int m = 1; m < 32; m <<= 1) var += __shfl_xor(var, m);
    float rs = 1.0f / sqrtf(var * (1.0f / 128.0f) + 1e-5f);
    return make_float4(d0 * rs, d1 * rs, d2 * rs, d3 * rs);
}

// ================= k0': cond GEMMs (14 units) + zb + fused layer-0 pre =================
// [0,1344):    cond: 8 XCD x 12 tiles(32r) x 14 units (kinds 0-3 of layer 0 dropped)
// [1344,1728): zb:   8 XCD x 12 j x 4 kk-chunks
// [1728,2304): fused layer-0 pre: 8 XCD x 12 tiles(32r) x 6 u (gate/beta inline -> x|y -> proj)
__global__ __launch_bounds__(256) void k0_cond(Params P)
{
    __shared__ __align__(16) float smA[32 * 132];
    __shared__ __align__(16) float wzg[204];
    int tid = threadIdx.x, bid = blockIdx.x;
    const size_t NC = (size_t)NTOK * 128;
    if (bid < 1344) {
        int x8 = bid & 7, rest = bid >> 3;          // rest 0..167
        int tl = rest % 12, unit = rest / 12;       // unit 0..13
        int kind, i;
        if (unit < 8) { kind = unit >> 1; i = 1 + (unit & 1); }
        else          { int v = unit - 8; kind = 4 + v / 3; i = v % 3; }
        int row0 = (x8 * 12 + tl) * 32;
#pragma unroll
        for (int it = 0; it < 4; it++) {
            int fo = (tid + it * 256) * 4, r = fo >> 7, c = fo & 127;
            *(float4*)&smA[r * 132 + c] = *(const float4*)&P.cl[(size_t)(row0 + r) * 128 + c];
        }
        __syncthreads();
        int hw = tid >> 5, cq = (tid & 31) * 4;
#pragma unroll
        for (int rr = 0; rr < 4; rr++) {
            int r = hw * 4 + rr;
            float4 n = ln_row32(*(float4*)&smA[r * 132 + cq]);
            *(float4*)&smA[r * 132 + cq] = n;
        }
        __syncthreads();
        const float* W; const float* bias = nullptr; bool dosig = false;
        switch (kind) {
            case 0:  W = P.ada_g_w  + (size_t)i * 16384; bias = P.ada_g_b  + i * 128; dosig = true; break;
            case 1:  W = P.ada_b_w  + (size_t)i * 16384; break;
            case 2:  W = P.ada2_g_w + (size_t)i * 16384; bias = P.ada2_g_b + i * 128; dosig = true; break;
            case 3:  W = P.ada2_b_w + (size_t)i * 16384; break;
            case 4:  W = P.sg_w     + (size_t)i * 16384; bias = P.sg_b     + i * 128; dosig = true; break;
            default: W = P.sg2_w    + (size_t)i * 16384; bias = P.sg2_b    + i * 128; dosig = true; break;
        }
        W += cq;
        float acc[4][4] = {};
#pragma unroll 8
        for (int k = 0; k < 128; k++) {
            float4 w4 = *(const float4*)(W + (size_t)k * 128);
#pragma unroll
            for (int rr = 0; rr < 4; rr++) {
                float a = smA[(hw * 4 + rr) * 132 + k];
                acc[rr][0] = fmaf(a, w4.x, acc[rr][0]);
                acc[rr][1] = fmaf(a, w4.y, acc[rr][1]);
                acc[rr][2] = fmaf(a, w4.z, acc[rr][2]);
                acc[rr][3] = fmaf(a, w4.w, acc[rr][3]);
            }
        }
        float4 b4 = bias ? *(const float4*)&bias[cq] : make_float4(0, 0, 0, 0);
        float* dst = P.G + (size_t)(kind * NBLK + i) * NC;
#pragma unroll
        for (int rr = 0; rr < 4; rr++) {
            float4 o = make_float4(acc[rr][0] + b4.x, acc[rr][1] + b4.y,
                                   acc[rr][2] + b4.z, acc[rr][3] + b4.w);
            if (dosig) { o.x = sig(o.x); o.y = sig(o.y); o.z = sig(o.z); o.w = sig(o.w); }
            *(float4*)&dst[(size_t)(row0 + hw * 4 + rr) * 128 + cq] = o;
        }
    } else if (bid < 1728) {
        int b2 = bid - 1344;
        int x8 = b2 & 7, rest = b2 >> 3;    // rest 0..47
        int jl = rest >> 2, kkc = rest & 3;
        int j = x8 * 12 + jl;
        if (tid < 192) {
            int i3 = tid >> 6, rem = tid & 63, c = rem >> 2, h = rem & 3;
            wzg[(i3 * 16 + c) * 4 + h] = P.z_ln_g[i3 * 16 + c] * P.wz[(i3 * 16 + c) * 4 + h];
        }
        if (tid < 12) {
            int i3 = tid >> 2, h = tid & 3;
            float s = 0.0f;
            for (int c = 0; c < 16; c++) s += P.z_ln_b[i3 * 16 + c] * P.wz[(i3 * 16 + c) * 4 + h];
            wzg[192 + tid] = s;
        }
        __syncthreads();
        int kstart = max(0, j * 32 - 48);
        int W = min(NTOK, j * 32 + 80) - kstart;
#pragma unroll
        for (int it = 0; it < 4; it++) {
            int idx = tid + it * 256;
            int qi = idx >> 5, kk = kkc * 32 + (idx & 31);
            if (kk >= W) continue;
            int q = j * 32 + qi;
            const float* src = P.plm + ((size_t)q * NTOK + (size_t)(kstart + kk)) * 16;
            float xv[16];
            *(float4*)(xv + 0)  = *(const float4*)(src + 0);
            *(float4*)(xv + 4)  = *(const float4*)(src + 4);
            *(float4*)(xv + 8)  = *(const float4*)(src + 8);
            *(float4*)(xv + 12) = *(const float4*)(src + 12);
            float s = 0.0f;
#pragma unroll
            for (int c = 0; c < 16; c++) s += xv[c];
            float mean = s * (1.0f / 16.0f);
            float var = 0.0f;
#pragma unroll
            for (int c = 0; c < 16; c++) { float d = xv[c] - mean; var += d * d; }
            float rs = 1.0f / sqrtf(var * (1.0f / 16.0f) + 1e-5f);
#pragma unroll
            for (int c = 0; c < 16; c++) xv[c] = (xv[c] - mean) * rs;
#pragma unroll
            for (int i3 = 0; i3 < NBLK; i3++) {
#pragma unroll
                for (int h = 0; h < 4; h++) {
                    float o = wzg[192 + i3 * 4 + h];
#pragma unroll
                    for (int c = 0; c < 16; c++) o = fmaf(xv[c], wzg[(i3 * 16 + c) * 4 + h], o);
                    P.zb[((size_t)(i3 * 4 + h) * NTOK + q) * 128 + kk] = o;
                }
            }
        }
    } else {
        // fused layer-0 pre: gate/beta inline, then x|y, then projection
        int b2 = bid - 1728;
        int x8 = b2 & 7, rest = b2 >> 3;    // 0..71
        int tl = rest % 12, u = rest / 12;  // u 0..5
        int row0 = (x8 * 12 + tl) * 32;
        int hw = tid >> 5, cq = (tid & 31) * 4;
#pragma unroll
        for (int it = 0; it < 4; it++) {
            int fo = (tid + it * 256) * 4, r = fo >> 7, c = fo & 127;
            *(float4*)&smA[r * 132 + c] = *(const float4*)&P.cl[(size_t)(row0 + r) * 128 + c];
        }
        __syncthreads();
#pragma unroll
        for (int rr = 0; rr < 4; rr++) {
            int r = hw * 4 + rr;
            float4 n = ln_row32(*(float4*)&smA[r * 132 + cq]);
            *(float4*)&smA[r * 132 + cq] = n;
        }
        __syncthreads();
        const float* Wg = (u < 4 ? P.ada_g_w : P.ada2_g_w) + cq;   // layer 0
        const float* Wb = (u < 4 ? P.ada_b_w : P.ada2_b_w) + cq;
        const float* bg = (u < 4 ? P.ada_g_b : P.ada2_g_b);
        float ga[4][4] = {}, ba[4][4] = {};
#pragma unroll 4
        for (int k = 0; k < 128; k++) {
            float4 wg4 = *(const float4*)(Wg + (size_t)k * 128);
            float4 wb4 = *(const float4*)(Wb + (size_t)k * 128);
#pragma unroll
            for (int rr = 0; rr < 4; rr++) {
                float a = smA[(hw * 4 + rr) * 132 + k];
                ga[rr][0] = fmaf(a, wg4.x, ga[rr][0]);
                ga[rr][1] = fmaf(a, wg4.y, ga[rr][1]);
                ga[rr][2] = fmaf(a, wg4.z, ga[rr][2]);
                ga[rr][3] = fmaf(a, wg4.w, ga[rr][3]);
                ba[rr][0] = fmaf(a, wb4.x, ba[rr][0]);
                ba[rr][1] = fmaf(a, wb4.y, ba[rr][1]);
                ba[rr][2] = fmaf(a, wb4.z, ba[rr][2]);
                ba[rr][3] = fmaf(a, wb4.w, ba[rr][3]);
            }
        }
        __syncthreads();   // done reading LN(cl); smA will be overwritten with x|y
        {
            float4 bg4 = *(const float4*)&bg[cq];
#pragma unroll
            for (int rr = 0; rr < 4; rr++) {
                int r = row0 + hw * 4 + rr;
                float4 ln4 = ln_row32(*(const float4*)&P.ql[(size_t)r * 128 + cq]);
                float4 x4;
                x4.x = fmaf(sig(ga[rr][0] + bg4.x), ln4.x, ba[rr][0]);
                x4.y = fmaf(sig(ga[rr][1] + bg4.y), ln4.y, ba[rr][1]);
                x4.z = fmaf(sig(ga[rr][2] + bg4.z), ln4.z, ba[rr][2]);
                x4.w = fmaf(sig(ga[rr][3] + bg4.w), ln4.w, ba[rr][3]);
                *(float4*)&smA[(hw * 4 + rr) * 132 + cq] = x4;
            }
        }
        __syncthreads();
        if (u < 4) {
            const float* W = (u == 0 ? P.wq : u == 1 ? P.wk : u == 2 ? P.wv : P.wg) + cq;
            float acc[4][4] = {};
#pragma unroll 8
            for (int k = 0; k < 128; k++) {
                float4 w4 = *(const float4*)(W + (size_t)k * 128);
#pragma unroll
                for (int rr = 0; rr < 4; rr++) {
                    float a = smA[(hw * 4 + rr) * 132 + k];
                    acc[rr][0] = fmaf(a, w4.x, acc[rr][0]);
                    acc[rr][1] = fmaf(a, w4.y, acc[rr][1]);
                    acc[rr][2] = fmaf(a, w4.z, acc[rr][2]);
                    acc[rr][3] = fmaf(a, w4.w, acc[rr][3]);
                }
            }
            float4 b4 = (u == 0) ? *(const float4*)&P.bq[cq] : make_float4(0, 0, 0, 0);
#pragma unroll
            for (int rr = 0; rr < 4; rr++) {
                int r = row0 + hw * 4 + rr;
                *(float4*)&P.qkvg[(size_t)r * 512 + u * 128 + cq] =
                    make_float4(acc[rr][0] + b4.x, acc[rr][1] + b4.y,
                                acc[rr][2] + b4.z, acc[rr][3] + b4.w);
            }
        } else {
            int ch = (u - 4) * 128;
            const float* W1 = P.ff1 + ch + cq;
            const float* W2 = P.ff2 + ch + cq;
            float a1[4][4] = {}, a2[4][4] = {};
#pragma unroll 4
            for (int k = 0; k < 128; k++) {
                float4 w14 = *(const float4*)(W1 + (size_t)k * 256);
                float4 w24 = *(const float4*)(W2 + (size_t)k * 256);
#pragma unroll
                for (int rr = 0; rr < 4; rr++) {
                    float a = smA[(hw * 4 + rr) * 132 + k];
                    a1[rr][0] = fmaf(a, w14.x, a1[rr][0]);
                    a1[rr][1] = fmaf(a, w14.y, a1[rr][1]);
                    a1[rr][2] = fmaf(a, w14.z, a1[rr][2]);
                    a1[rr][3] = fmaf(a, w14.w, a1[rr][3]);
                    a2[rr][0] = fmaf(a, w24.x, a2[rr][0]);
                    a2[rr][1] = fmaf(a, w24.y, a2[rr][1]);
                    a2[rr][2] = fmaf(a, w24.z, a2[rr][2]);
                    a2[rr][3] = fmaf(a, w24.w, a2[rr][3]);
                }
            }
#pragma unroll
            for (int rr = 0; rr < 4; rr++) {
                int r = row0 + hw * 4 + rr;
                float4 o;
                o.x = a1[rr][0] * sig(a1[rr][0]) * a2[rr][0];
                o.y = a1[rr][1] * sig(a1[rr][1]) * a2[rr][1];
                o.z = a1[rr][2] * sig(a1[rr][2]) * a2[rr][2];
                o.w = a1[rr][3] * sig(a1[rr][3]) * a2[rr][3];
                *(float4*)&P.ffb[(size_t)r * 256 + ch + cq] = o;
            }
        }
    }
}

// ================= kA: x|y elementwise + single projection GEMM (layers 1,2) ==========
// grid 576 = 8 XCD x 12 tiles(32 rows) x 6 units {q,k,v,g, ff-lo, ff-hi}
// a_prev reconstructed in-register: G4·(Σ_h bout4) + tpart
__global__ __launch_bounds__(256) void kA_pre(Params P, int i)
{
    __shared__ __align__(16) float smX[32 * 132];
    const size_t NC = (size_t)NTOK * 128;
    int tid = threadIdx.x, bid = blockIdx.x;
    int x8 = bid & 7, rest = bid >> 3;      // 0..71
    int tl = rest % 12, u = rest / 12;      // u 0..5
    int row0 = (x8 * 12 + tl) * 32;
    int hw = tid >> 5, cq = (tid & 31) * 4;
    const float* Gg = P.G + (size_t)(((u < 4 ? 0 : 2) * NBLK) + i) * NC;
    const float* Gb = P.G + (size_t)(((u < 4 ? 1 : 3) * NBLK) + i) * NC;
    const float* G4p = P.G + (size_t)(4 * NBLK + (i - 1)) * NC;   // prev layer's sig(sg)
#pragma unroll
    for (int rr = 0; rr < 4; rr++) {
        int r = row0 + hw * 4 + rr;
        size_t off = (size_t)r * 128 + cq;
        float4 p0 = *(const float4*)&P.bout4[off];
        float4 p1 = *(const float4*)&P.bout4[NC + off];
        float4 p2 = *(const float4*)&P.bout4[2 * NC + off];
        float4 p3 = *(const float4*)&P.bout4[3 * NC + off];
        float4 tp = *(const float4*)&P.tpart[off];
        float4 gs = *(const float4*)&G4p[off];
        float4 a4;
        a4.x = fmaf(gs.x, p0.x + p1.x + p2.x + p3.x, tp.x);
        a4.y = fmaf(gs.y, p0.y + p1.y + p2.y + p3.y, tp.y);
        a4.z = fmaf(gs.z, p0.z + p1.z + p2.z + p3.z, tp.z);
        a4.w = fmaf(gs.w, p0.w + p1.w + p2.w + p3.w, tp.w);
        float4 ln4 = ln_row32(a4);
        float4 g4 = *(const float4*)&Gg[off];
        float4 b4 = *(const float4*)&Gb[off];
        float4 x4;
        x4.x = fmaf(g4.x, ln4.x, b4.x);
        x4.y = fmaf(g4.y, ln4.y, b4.y);
        x4.z = fmaf(g4.z, ln4.z, b4.z);
        x4.w = fmaf(g4.w, ln4.w, b4.w);
        *(float4*)&smX[(hw * 4 + rr) * 132 + cq] = x4;
    }
    __syncthreads();
    if (u < 4) {
        const float* W = (u == 0 ? P.wq : u == 1 ? P.wk : u == 2 ? P.wv : P.wg)
                         + (size_t)i * 16384 + cq;
        float acc[4][4] = {};
#pragma unroll 8
        for (int k = 0; k < 128; k++) {
            float4 w4 = *(const float4*)(W + (size_t)k * 128);
#pragma unroll
            for (int rr = 0; rr < 4; rr++) {
                float a = smX[(hw * 4 + rr) * 132 + k];
                acc[rr][0] = fmaf(a, w4.x, acc[rr][0]);
                acc[rr][1] = fmaf(a, w4.y, acc[rr][1]);
                acc[rr][2] = fmaf(a, w4.z, acc[rr][2]);
                acc[rr][3] = fmaf(a, w4.w, acc[rr][3]);
            }
        }
        float4 b4 = (u == 0) ? *(const float4*)&P.bq[(size_t)i * 128 + cq]
                             : make_float4(0, 0, 0, 0);
#pragma unroll
        for (int rr = 0; rr < 4; rr++) {
            int r = row0 + hw * 4 + rr;
            *(float4*)&P.qkvg[(size_t)r * 512 + u * 128 + cq] =
                make_float4(acc[rr][0] + b4.x, acc[rr][1] + b4.y,
                            acc[rr][2] + b4.z, acc[rr][3] + b4.w);
        }
    } else {
        int ch = (u - 4) * 128;
        const float* W1 = P.ff1 + (size_t)i * 32768 + ch + cq;
        const float* W2 = P.ff2 + (size_t)i * 32768 + ch + cq;
        float a1[4][4] = {}, a2[4][4] = {};
#pragma unroll 4
        for (int k = 0; k < 128; k++) {
            float4 w14 = *(const float4*)(W1 + (size_t)k * 256);
            float4 w24 = *(const float4*)(W2 + (size_t)k * 256);
#pragma unroll
            for (int rr = 0; rr < 4; rr++) {
                float a = smX[(hw * 4 + rr) * 132 + k];
                a1[rr][0] = fmaf(a, w14.x, a1[rr][0]);
                a1[rr][1] = fmaf(a, w14.y, a1[rr][1]);
                a1[rr][2] = fmaf(a, w14.z, a1[rr][2]);
                a1[rr][3] = fmaf(a, w14.w, a1[rr][3]);
                a2[rr][0] = fmaf(a, w24.x, a2[rr][0]);
                a2[rr][1] = fmaf(a, w24.y, a2[rr][1]);
                a2[rr][2] = fmaf(a, w24.z, a2[rr][2]);
                a2[rr][3] = fmaf(a, w24.w, a2[rr][3]);
            }
        }
#pragma unroll
        for (int rr = 0; rr < 4; rr++) {
            int r = row0 + hw * 4 + rr;
            float4 o;
            o.x = a1[rr][0] * sig(a1[rr][0]) * a2[rr][0];
            o.y = a1[rr][1] * sig(a1[rr][1]) * a2[rr][1];
            o.z = a1[rr][2] * sig(a1[rr][2]) * a2[rr][2];
            o.w = a1[rr][3] * sig(a1[rr][3]) * a2[rr][3];
            *(float4*)&P.ffb[(size_t)r * 256 + ch + cq] = o;
        }
    }
}

// ================= kB: attention + per-head wo partial (blocks 0..767)
//                      + tpart = sig(sg2)·(ffb@ff3)   (blocks 768..1151) ==================
__global__ __launch_bounds__(256) void kB_attn(Params P, int i)
{
    __shared__ __align__(16) float sm[11344];   // ks[4608] | vs[4608] | ps[16*133]; union tpart [16*260]
    const size_t NC = (size_t)NTOK * 128;
    int tid = threadIdx.x, bid = blockIdx.x;
    if (bid < 768) {
        float* ks = sm;             // [128][36]; reused as o_s[16][33] after QK^T/PV
        float* vs = sm + 4608;      // [128][36]
        float* ps = sm + 9216;      // [16][PSS]
        int x8 = bid & 7, g = bid >> 3;            // 0..95
        int jl = g >> 3, rem = g & 7;
        int h = rem >> 1, qh = rem & 1;
        int jglob = x8 * 12 + jl;
        int q0 = jglob * 32 + qh * 16;
        int kstart = max(0, jglob * 32 - 48);
        int W = min(NTOK, jglob * 32 + 80) - kstart;
        for (int idx = tid; idx < W * 8; idx += 256) {
            int kk = idx >> 3, d = (idx & 7) * 4;
            const float* base = &P.qkvg[(size_t)(kstart + kk) * 512 + 128 + h * 32 + d];
            float4 tK = *(const float4*)base;
            float4 tV = *(const float4*)(base + 128);
            *(float4*)&ks[kk * 36 + d] = tK;
            *(float4*)&vs[kk * 36 + d] = tV;
        }
        const float* zbase = &P.zb[((size_t)(i * 4 + h) * NTOK + q0) * 128];
#pragma unroll
        for (int it = 0; it < 2; it++) {
            int idx = tid + it * 256;
            int r = idx >> 5, c4 = (idx & 31) * 4;
            float4 z4 = *(const float4*)&zbase[(size_t)r * 128 + c4];
            ps[r * PSS + c4]     = z4.x;
            ps[r * PSS + c4 + 1] = z4.y;
            ps[r * PSS + c4 + 2] = z4.z;
            ps[r * PSS + c4 + 3] = z4.w;
        }
        int qi = tid & 15, kg = tid >> 4;
        float qreg[32];
        {
            const float* qp = &P.qkvg[(size_t)(q0 + qi) * 512 + h * 32];
#pragma unroll
            for (int d4 = 0; d4 < 8; d4++) {
                float4 tq = *(const float4*)(qp + d4 * 4);
                qreg[d4 * 4] = tq.x; qreg[d4 * 4 + 1] = tq.y;
                qreg[d4 * 4 + 2] = tq.z; qreg[d4 * 4 + 3] = tq.w;
            }
        }
        __syncthreads();
        const float scale = 0.17677669529663687f;  // 1/sqrt(32)
#pragma unroll
        for (int t2 = 0; t2 < 8; t2++) {
            int kk = kg + t2 * 16;
            if (kk < W) {
                float acc = 0.0f;
#pragma unroll
                for (int d4 = 0; d4 < 8; d4++) {
                    float4 kv = *(const float4*)&ks[kk * 36 + d4 * 4];
                    acc = fmaf(qreg[d4 * 4 + 0], kv.x, acc);
                    acc = fmaf(qreg[d4 * 4 + 1], kv.y, acc);
                    acc = fmaf(qreg[d4 * 4 + 2], kv.z, acc);
                    acc = fmaf(qreg[d4 * 4 + 3], kv.w, acc);
                }
                ps[qi * PSS + kk] = fmaf(acc, scale, ps[qi * PSS + kk]);
            }
        }
        __syncthreads();
        {
            int row = tid >> 4, sub = tid & 15;
            float m = -3.0e38f;
            for (int kk = sub; kk < W; kk += 16) m = fmaxf(m, ps[row * PSS + kk]);
#pragma unroll
            for (int s2 = 1; s2 < 16; s2 <<= 1) m = fmaxf(m, __shfl_xor(m, s2));
            float ssum = 0.0f;
            for (int kk = sub; kk < W; kk += 16) {
                float e = expf(ps[row * PSS + kk] - m);
                ps[row * PSS + kk] = e; ssum += e;
            }
#pragma unroll
            for (int s2 = 1; s2 < 16; s2 <<= 1) ssum += __shfl_xor(ssum, s2);
            float rinv = 1.0f / ssum;
            for (int kk = sub; kk < W; kk += 16) ps[row * PSS + kk] *= rinv;
        }
        __syncthreads();
        {
            int dg = tid >> 4, d0 = dg * 2;
            float o0 = 0.0f, o1 = 0.0f, o0b = 0.0f, o1b = 0.0f;
            for (int kk = 0; kk + 1 < W; kk += 2) {
                float p0 = ps[qi * PSS + kk], p1 = ps[qi * PSS + kk + 1];
                float2 va = *(const float2*)&vs[kk * 36 + d0];
                float2 vb = *(const float2*)&vs[(kk + 1) * 36 + d0];
                o0  = fmaf(p0, va.x, o0);  o1  = fmaf(p0, va.y, o1);
                o0b = fmaf(p1, vb.x, o0b); o1b = fmaf(p1, vb.y, o1b);
            }
            if (W & 1) {
                float p0 = ps[qi * PSS + W - 1];
                float2 va = *(const float2*)&vs[(W - 1) * 36 + d0];
                o0 = fmaf(p0, va.x, o0); o1 = fmaf(p0, va.y, o1);
            }
            o0 += o0b; o1 += o1b;
            float2 g2 = *(const float2*)&P.qkvg[(size_t)(q0 + qi) * 512 + 384 + h * 32 + d0];
            // g-gated head output -> LDS (ks region is dead after QK^T)
            ks[qi * 33 + d0]     = o0 * sig(g2.x);
            ks[qi * 33 + d0 + 1] = o1 * sig(g2.y);
        }
        __syncthreads();
        // per-head wo partial: bout4[h][q0+r][c] = sum_d o_s[r][d] * wo[h*32+d][c]
        {
            int r = tid >> 4, ci = tid & 15;
            int c0 = ci * 8;
            const float* o_s = ks;
            const float* wop = P.wo + (size_t)i * 16384 + (size_t)(h * 32) * 128 + c0;
            float acc[8] = {};
#pragma unroll 4
            for (int d = 0; d < 32; d++) {
                float a = o_s[r * 33 + d];
                float4 w0 = *(const float4*)(wop + (size_t)d * 128);
                float4 w1 = *(const float4*)(wop + (size_t)d * 128 + 4);
                acc[0] = fmaf(a, w0.x, acc[0]); acc[1] = fmaf(a, w0.y, acc[1]);
                acc[2] = fmaf(a, w0.z, acc[2]); acc[3] = fmaf(a, w0.w, acc[3]);
                acc[4] = fmaf(a, w1.x, acc[4]); acc[5] = fmaf(a, w1.y, acc[5]);
                acc[6] = fmaf(a, w1.z, acc[6]); acc[7] = fmaf(a, w1.w, acc[7]);
            }
            float* dst = P.bout4 + (size_t)h * NC + (size_t)(q0 + r) * 128 + c0;
            *(float4*)dst       = make_float4(acc[0], acc[1], acc[2], acc[3]);
            *(float4*)(dst + 4) = make_float4(acc[4], acc[5], acc[6], acc[7]);
        }
    } else {
        // tpart = sig(sg2)·(ffb @ ff3): 384 blocks = 8 XCD x 24 tiles(16r) x 2 col-halves(64)
        float* smC = sm;   // [16][260]
        int b2 = bid - 768;
        int x8 = b2 & 7, rest = b2 >> 3;    // 0..47
        int tl = rest >> 1, chalf = rest & 1;
        int row0 = x8 * 384 + tl * 16;
#pragma unroll
        for (int it = 0; it < 4; it++) {
            int fo = (tid + it * 256) * 4, r = fo >> 8, c = fo & 255;
            *(float4*)&smC[r * 260 + c] = *(const float4*)&P.ffb[(size_t)(row0 + r) * 256 + c];
        }
        __syncthreads();
        int r = tid >> 4, c = chalf * 64 + (tid & 15) * 4;
        const float* f3_p = P.ff3 + (size_t)i * 32768 + c;
        float acc[4] = {};
#pragma unroll 8
        for (int k = 0; k < 256; k++) {
            float4 w4 = *(const float4*)(f3_p + (size_t)k * 128);
            float a = smC[r * 260 + k];
            acc[0] = fmaf(a, w4.x, acc[0]);
            acc[1] = fmaf(a, w4.y, acc[1]);
            acc[2] = fmaf(a, w4.z, acc[2]);
            acc[3] = fmaf(a, w4.w, acc[3]);
        }
        int row = row0 + r;
        float4 g5 = *(const float4*)&P.G[(size_t)(5 * NBLK + i) * NC + (size_t)row * 128 + c];
        *(float4*)&P.tpart[(size_t)row * 128 + c] =
            make_float4(g5.x * acc[0], g5.y * acc[1], g5.z * acc[2], g5.w * acc[3]);
    }
}

// ================= kC: final combine out = G4·Σ bout4 + tpart (layer NBLK-1) ==============
__global__ __launch_bounds__(256) void kC_out(Params P)
{
    const size_t NC = (size_t)NTOK * 128;
    int idx = blockIdx.x * 256 + threadIdx.x;
    int r = idx >> 5, cq = (idx & 31) * 4;
    size_t off = (size_t)r * 128 + cq;
    float4 p0 = *(const float4*)&P.bout4[off];
    float4 p1 = *(const float4*)&P.bout4[NC + off];
    float4 p2 = *(const float4*)&P.bout4[2 * NC + off];
    float4 p3 = *(const float4*)&P.bout4[3 * NC + off];
    float4 tp = *(const float4*)&P.tpart[off];
    float4 gs = *(const float4*)&P.G[(size_t)(4 * NBLK + (NBLK - 1)) * NC + off];
    float4 o;
    o.x = fmaf(gs.x, p0.x + p1.x + p2.x + p3.x, tp.x);
    o.y = fmaf(gs.y, p0.y + p1.y + p2.y + p3.y, tp.y);
    o.z = fmaf(gs.z, p0.z + p1.z + p2.z + p3.z, tp.z);
    o.w = fmaf(gs.w, p0.w + p1.w + p2.w + p3.w, tp.w);
    *(float4*)&P.out[off] = o;
}

extern "C" void kernel_launch(void* const* d_in, const int* in_sizes, int n_in,
                              void* d_out, int out_size, void* d_ws, size_t ws_size,
                              hipStream_t stream)
{
    Params P;
    P.ql       = (const float*)d_in[0];
    P.cl       = (const float*)d_in[1];
    P.plm      = (const float*)d_in[2];
    P.ada_g_w  = (const float*)d_in[3];
    P.ada_g_b  = (const float*)d_in[4];
    P.ada_b_w  = (const float*)d_in[5];
    P.wq       = (const float*)d_in[6];
    P.bq       = (const float*)d_in[7];
    P.wk       = (const float*)d_in[8];
    P.wv       = (const float*)d_in[9];
    P.z_ln_g   = (const float*)d_in[10];
    P.z_ln_b   = (const float*)d_in[11];
    P.wz       = (const float*)d_in[12];
    P.wg       = (const float*)d_in[13];
    P.wo       = (const float*)d_in[14];
    P.sg_w     = (const float*)d_in[15];
    P.sg_b     = (const float*)d_in[16];
    P.ada2_g_w = (const float*)d_in[17];
    P.ada2_g_b = (const float*)d_in[18];
    P.ada2_b_w = (const float*)d_in[19];
    P.ff1      = (const float*)d_in[20];
    P.ff2      = (const float*)d_in[21];
    P.ff3      = (const float*)d_in[22];
    P.sg2_w    = (const float*)d_in[23];
    P.sg2_b    = (const float*)d_in[24];

    float* ws = (float*)d_ws;
    const size_t NC = (size_t)NTOK * 128;
    P.qkvg  = ws;             // N x 512
    P.ffb   = ws + 4 * NC;    // N x 256
    P.zb    = ws + 6 * NC;    // 3 x 4 x N x 128
    P.G     = ws + 18 * NC;   // 18 x N x 128 (6 kinds x 3 layers)
    P.bout4 = ws + 36 * NC;   // 4 x N x 128 (per-head wo partials)
    P.tpart = ws + 40 * NC;   // N x 128
    P.out   = (float*)d_out;

    k0_cond<<<2304, 256, 0, stream>>>(P);
    kB_attn<<<1152, 256, 0, stream>>>(P, 0);
    for (int i = 1; i < NBLK; i++) {
        kA_pre<<<576, 256, 0, stream>>>(P, i);
        kB_attn<<<1152, 256, 0, stream>>>(P, i);
    }
    kC_out<<<384, 256, 0, stream>>>(P);
}

// Round 14
// 276.370 us; speedup vs baseline: 1.2624x; 1.0074x over previous
//
#include <hip/hip_runtime.h>
#include <cmath>

#define NTOK 3072
#define NBLK 3
#define PSS 133   // ps LDS stride: %32 == 5 -> conflict-free reads

__device__ __forceinline__ float sig(float v) { return 1.0f / (1.0f + expf(-v)); }

struct Params {
    const float *ql, *cl, *plm;
    const float *ada_g_w, *ada_g_b, *ada_b_w;
    const float *wq, *bq, *wk, *wv;
    const float *z_ln_g, *z_ln_b, *wz;
    const float *wg, *wo, *sg_w, *sg_b;
    const float *ada2_g_w, *ada2_g_b, *ada2_b_w;
    const float *ff1, *ff2, *ff3, *sg2_w, *sg2_b;
    float *qkvg, *ffb, *zb, *G, *bout4, *tpart;
    float *out;
};

// 32-lane-subgroup row LN of 4 register values (cols (lane&31)*4 .. +3 of a 128-col row)
__device__ __forceinline__ float4 ln_row32(float4 v)
{
    float s = v.x + v.y + v.z + v.w;
#pragma unroll
    for (int m = 1; m < 32; m <<= 1) s += __shfl_xor(s, m);
    float mean = s * (1.0f / 128.0f);
    float d0 = v.x - mean, d1 = v.y - mean, d2 = v.z - mean, d3 = v.w - mean;
    float var = d0 * d0 + d1 * d1 + d2 * d2 + d3 * d3;
#pragma unroll
    for (int m = 1; m < 32; m <<= 1) var += __shfl_xor(var, m);
    float rs = 1.0f / sqrtf(var * (1.0f / 128.0f) + 1e-5f);
    return make_float4(d0 * rs, d1 * rs, d2 * rs, d3 * rs);
}

// ---- shared cond-GEMM body: one (kind, layer) unit over a 32-row tile ----
__device__ __forceinline__ void cond_unit(const Params& P, float* smA, int tid,
                                          int kind, int i, int row0)
{
    const size_t NC = (size_t)NTOK * 128;
#pragma unroll
    for (int it = 0; it < 4; it++) {
        int fo = (tid + it * 256) * 4, r = fo >> 7, c = fo & 127;
        *(float4*)&smA[r * 132 + c] = *(const float4*)&P.cl[(size_t)(row0 + r) * 128 + c];
    }
    __syncthreads();
    int hw = tid >> 5, cq = (tid & 31) * 4;
#pragma unroll
    for (int rr = 0; rr < 4; rr++) {
        int r = hw * 4 + rr;
        float4 n = ln_row32(*(float4*)&smA[r * 132 + cq]);
        *(float4*)&smA[r * 132 + cq] = n;
    }
    __syncthreads();
    const float* W; const float* bias = nullptr; bool dosig = false;
    switch (kind) {
        case 0:  W = P.ada_g_w  + (size_t)i * 16384; bias = P.ada_g_b  + i * 128; dosig = true; break;
        case 1:  W = P.ada_b_w  + (size_t)i * 16384; break;
        case 2:  W = P.ada2_g_w + (size_t)i * 16384; bias = P.ada2_g_b + i * 128; dosig = true; break;
        case 3:  W = P.ada2_b_w + (size_t)i * 16384; break;
        case 4:  W = P.sg_w     + (size_t)i * 16384; bias = P.sg_b     + i * 128; dosig = true; break;
        default: W = P.sg2_w    + (size_t)i * 16384; bias = P.sg2_b    + i * 128; dosig = true; break;
    }
    W += cq;
    float acc[4][4] = {};
#pragma unroll 8
    for (int k = 0; k < 128; k++) {
        float4 w4 = *(const float4*)(W + (size_t)k * 128);
#pragma unroll
        for (int rr = 0; rr < 4; rr++) {
            float a = smA[(hw * 4 + rr) * 132 + k];
            acc[rr][0] = fmaf(a, w4.x, acc[rr][0]);
            acc[rr][1] = fmaf(a, w4.y, acc[rr][1]);
            acc[rr][2] = fmaf(a, w4.z, acc[rr][2]);
            acc[rr][3] = fmaf(a, w4.w, acc[rr][3]);
        }
    }
    float4 b4 = bias ? *(const float4*)&bias[cq] : make_float4(0, 0, 0, 0);
    float* dst = P.G + (size_t)(kind * NBLK + i) * NC;
#pragma unroll
    for (int rr = 0; rr < 4; rr++) {
        float4 o = make_float4(acc[rr][0] + b4.x, acc[rr][1] + b4.y,
                               acc[rr][2] + b4.z, acc[rr][3] + b4.w);
        if (dosig) { o.x = sig(o.x); o.y = sig(o.y); o.z = sig(o.z); o.w = sig(o.w); }
        *(float4*)&dst[(size_t)(row0 + hw * 4 + rr) * 128 + cq] = o;
    }
}

// ================= kInit: ONLY what kA(0) needs — cond kinds 0-3 layer 0 =================
// grid 384 = 8 XCD x 12 tiles(32r) x 4 kinds
__global__ __launch_bounds__(256) void kInit(Params P)
{
    __shared__ __align__(16) float smA[32 * 132];
    int tid = threadIdx.x, bid = blockIdx.x;
    int x8 = bid & 7, rest = bid >> 3;   // 0..47
    int tl = rest % 12, kind = rest / 12;
    int row0 = (x8 * 12 + tl) * 32;
    cond_unit(P, smA, tid, kind, 0, row0);
}

// ================= kA: pre (576) [+ i==0: deferred cond (1344) + zb (384)] ==========
// pre: 8 XCD x 12 tiles(32r) x 6 units, heavy-first (u = 5 - rest/12)
//   i==0: a_prev = ql; i>0: recon G4·(Σ_h bout4) + tpart
__global__ __launch_bounds__(256) void kA_pre(Params P, int i)
{
    __shared__ __align__(16) float smX[32 * 132];
    __shared__ __align__(16) float wzg[204];
    const size_t NC = (size_t)NTOK * 128;
    int tid = threadIdx.x, bid = blockIdx.x;
    if (bid < 576) {
        int x8 = bid & 7, rest = bid >> 3;      // 0..71
        int tl = rest % 12, u = 5 - rest / 12;  // heavy ffb units dispatch first
        int row0 = (x8 * 12 + tl) * 32;
        int hw = tid >> 5, cq = (tid & 31) * 4;
        const float* Gg = P.G + (size_t)(((u < 4 ? 0 : 2) * NBLK) + i) * NC;
        const float* Gb = P.G + (size_t)(((u < 4 ? 1 : 3) * NBLK) + i) * NC;
        const float* G4p = P.G + (size_t)(4 * NBLK + (i > 0 ? i - 1 : 0)) * NC;
#pragma unroll
        for (int rr = 0; rr < 4; rr++) {
            int r = row0 + hw * 4 + rr;
            size_t off = (size_t)r * 128 + cq;
            float4 a4;
            if (i == 0) {
                a4 = *(const float4*)&P.ql[off];
            } else {
                float4 p0 = *(const float4*)&P.bout4[off];
                float4 p1 = *(const float4*)&P.bout4[NC + off];
                float4 p2 = *(const float4*)&P.bout4[2 * NC + off];
                float4 p3 = *(const float4*)&P.bout4[3 * NC + off];
                float4 tp = *(const float4*)&P.tpart[off];
                float4 gs = *(const float4*)&G4p[off];
                a4.x = fmaf(gs.x, p0.x + p1.x + p2.x + p3.x, tp.x);
                a4.y = fmaf(gs.y, p0.y + p1.y + p2.y + p3.y, tp.y);
                a4.z = fmaf(gs.z, p0.z + p1.z + p2.z + p3.z, tp.z);
                a4.w = fmaf(gs.w, p0.w + p1.w + p2.w + p3.w, tp.w);
            }
            float4 ln4 = ln_row32(a4);
            float4 g4 = *(const float4*)&Gg[off];
            float4 b4 = *(const float4*)&Gb[off];
            float4 x4;
            x4.x = fmaf(g4.x, ln4.x, b4.x);
            x4.y = fmaf(g4.y, ln4.y, b4.y);
            x4.z = fmaf(g4.z, ln4.z, b4.z);
            x4.w = fmaf(g4.w, ln4.w, b4.w);
            *(float4*)&smX[(hw * 4 + rr) * 132 + cq] = x4;
        }
        __syncthreads();
        if (u < 4) {
            const float* W = (u == 0 ? P.wq : u == 1 ? P.wk : u == 2 ? P.wv : P.wg)
                             + (size_t)i * 16384 + cq;
            float acc[4][4] = {};
#pragma unroll 8
            for (int k = 0; k < 128; k++) {
                float4 w4 = *(const float4*)(W + (size_t)k * 128);
#pragma unroll
                for (int rr = 0; rr < 4; rr++) {
                    float a = smX[(hw * 4 + rr) * 132 + k];
                    acc[rr][0] = fmaf(a, w4.x, acc[rr][0]);
                    acc[rr][1] = fmaf(a, w4.y, acc[rr][1]);
                    acc[rr][2] = fmaf(a, w4.z, acc[rr][2]);
                    acc[rr][3] = fmaf(a, w4.w, acc[rr][3]);
                }
            }
            float4 b4 = (u == 0) ? *(const float4*)&P.bq[(size_t)i * 128 + cq]
                                 : make_float4(0, 0, 0, 0);
#pragma unroll
            for (int rr = 0; rr < 4; rr++) {
                int r = row0 + hw * 4 + rr;
                *(float4*)&P.qkvg[(size_t)r * 512 + u * 128 + cq] =
                    make_float4(acc[rr][0] + b4.x, acc[rr][1] + b4.y,
                                acc[rr][2] + b4.z, acc[rr][3] + b4.w);
            }
        } else {
            int ch = (u - 4) * 128;
            const float* W1 = P.ff1 + (size_t)i * 32768 + ch + cq;
            const float* W2 = P.ff2 + (size_t)i * 32768 + ch + cq;
            float a1[4][4] = {}, a2[4][4] = {};
#pragma unroll 4
            for (int k = 0; k < 128; k++) {
                float4 w14 = *(const float4*)(W1 + (size_t)k * 256);
                float4 w24 = *(const float4*)(W2 + (size_t)k * 256);
#pragma unroll
                for (int rr = 0; rr < 4; rr++) {
                    float a = smX[(hw * 4 + rr) * 132 + k];
                    a1[rr][0] = fmaf(a, w14.x, a1[rr][0]);
                    a1[rr][1] = fmaf(a, w14.y, a1[rr][1]);
                    a1[rr][2] = fmaf(a, w14.z, a1[rr][2]);
                    a1[rr][3] = fmaf(a, w14.w, a1[rr][3]);
                    a2[rr][0] = fmaf(a, w24.x, a2[rr][0]);
                    a2[rr][1] = fmaf(a, w24.y, a2[rr][1]);
                    a2[rr][2] = fmaf(a, w24.z, a2[rr][2]);
                    a2[rr][3] = fmaf(a, w24.w, a2[rr][3]);
                }
            }
#pragma unroll
            for (int rr = 0; rr < 4; rr++) {
                int r = row0 + hw * 4 + rr;
                float4 o;
                o.x = a1[rr][0] * sig(a1[rr][0]) * a2[rr][0];
                o.y = a1[rr][1] * sig(a1[rr][1]) * a2[rr][1];
                o.z = a1[rr][2] * sig(a1[rr][2]) * a2[rr][2];
                o.w = a1[rr][3] * sig(a1[rr][3]) * a2[rr][3];
                *(float4*)&P.ffb[(size_t)r * 256 + ch + cq] = o;
            }
        }
    } else if (bid < 1920) {
        // deferred cond (i==0 launch only): kinds 0-3 x layers 1,2 (8) + kinds 4,5 x all (6)
        int b2 = bid - 576;
        int x8 = b2 & 7, rest = b2 >> 3;        // 0..167
        int tl = rest % 12, unit = rest / 12;   // 0..13
        int kind, il;
        if (unit < 8) { kind = unit >> 1; il = 1 + (unit & 1); }
        else          { int v = unit - 8; kind = 4 + v / 3; il = v % 3; }
        int row0 = (x8 * 12 + tl) * 32;
        cond_unit(P, smX, tid, kind, il, row0);
    } else {
        // zb (i==0 launch only): 8 XCD x 12 j x 4 kk-chunks
        int b3 = bid - 1920;
        int x8 = b3 & 7, rest = b3 >> 3;    // 0..47
        int jl = rest >> 2, kkc = rest & 3;
        int j = x8 * 12 + jl;
        if (tid < 192) {
            int i3 = tid >> 6, rem = tid & 63, c = rem >> 2, h = rem & 3;
            wzg[(i3 * 16 + c) * 4 + h] = P.z_ln_g[i3 * 16 + c] * P.wz[(i3 * 16 + c) * 4 + h];
        }
        if (tid < 12) {
            int i3 = tid >> 2, h = tid & 3;
            float s = 0.0f;
            for (int c = 0; c < 16; c++) s += P.z_ln_b[i3 * 16 + c] * P.wz[(i3 * 16 + c) * 4 + h];
            wzg[192 + tid] = s;
        }
        __syncthreads();
        int kstart = max(0, j * 32 - 48);
        int W = min(NTOK, j * 32 + 80) - kstart;
#pragma unroll
        for (int it = 0; it < 4; it++) {
            int idx = tid + it * 256;
            int qi = idx >> 5, kk = kkc * 32 + (idx & 31);
            if (kk >= W) continue;
            int q = j * 32 + qi;
            const float* src = P.plm + ((size_t)q * NTOK + (size_t)(kstart + kk)) * 16;
            float xv[16];
            *(float4*)(xv + 0)  = *(const float4*)(src + 0);
            *(float4*)(xv + 4)  = *(const float4*)(src + 4);
            *(float4*)(xv + 8)  = *(const float4*)(src + 8);
            *(float4*)(xv + 12) = *(const float4*)(src + 12);
            float s = 0.0f;
#pragma unroll
            for (int c = 0; c < 16; c++) s += xv[c];
            float mean = s * (1.0f / 16.0f);
            float var = 0.0f;
#pragma unroll
            for (int c = 0; c < 16; c++) { float d = xv[c] - mean; var += d * d; }
            float rs = 1.0f / sqrtf(var * (1.0f / 16.0f) + 1e-5f);
#pragma unroll
            for (int c = 0; c < 16; c++) xv[c] = (xv[c] - mean) * rs;
#pragma unroll
            for (int i3 = 0; i3 < NBLK; i3++) {
#pragma unroll
                for (int h = 0; h < 4; h++) {
                    float o = wzg[192 + i3 * 4 + h];
#pragma unroll
                    for (int c = 0; c < 16; c++) o = fmaf(xv[c], wzg[(i3 * 16 + c) * 4 + h], o);
                    P.zb[((size_t)(i3 * 4 + h) * NTOK + q) * 128 + kk] = o;
                }
            }
        }
    }
}

// ================= kB: attention + per-head wo partial (blocks 0..767)
//                      + tpart = sig(sg2)·(ffb@ff3)   (blocks 768..1151) ==================
__global__ __launch_bounds__(256) void kB_attn(Params P, int i)
{
    __shared__ __align__(16) float sm[11344];   // ks[4608] | vs[4608] | ps[16*133]; union tpart [16*260]
    const size_t NC = (size_t)NTOK * 128;
    int tid = threadIdx.x, bid = blockIdx.x;
    if (bid < 768) {
        float* ks = sm;             // [128][36]; reused as o_s[16][33] after QK^T/PV
        float* vs = sm + 4608;      // [128][36]
        float* ps = sm + 9216;      // [16][PSS]
        int x8 = bid & 7, g = bid >> 3;            // 0..95
        int jl = g >> 3, rem = g & 7;
        int h = rem >> 1, qh = rem & 1;
        int jglob = x8 * 12 + jl;
        int q0 = jglob * 32 + qh * 16;
        int kstart = max(0, jglob * 32 - 48);
        int W = min(NTOK, jglob * 32 + 80) - kstart;
        for (int idx = tid; idx < W * 8; idx += 256) {
            int kk = idx >> 3, d = (idx & 7) * 4;
            const float* base = &P.qkvg[(size_t)(kstart + kk) * 512 + 128 + h * 32 + d];
            float4 tK = *(const float4*)base;
            float4 tV = *(const float4*)(base + 128);
            *(float4*)&ks[kk * 36 + d] = tK;
            *(float4*)&vs[kk * 36 + d] = tV;
        }
        const float* zbase = &P.zb[((size_t)(i * 4 + h) * NTOK + q0) * 128];
#pragma unroll
        for (int it = 0; it < 2; it++) {
            int idx = tid + it * 256;
            int r = idx >> 5, c4 = (idx & 31) * 4;
            float4 z4 = *(const float4*)&zbase[(size_t)r * 128 + c4];
            ps[r * PSS + c4]     = z4.x;
            ps[r * PSS + c4 + 1] = z4.y;
            ps[r * PSS + c4 + 2] = z4.z;
            ps[r * PSS + c4 + 3] = z4.w;
        }
        int qi = tid & 15, kg = tid >> 4;
        float qreg[32];
        {
            const float* qp = &P.qkvg[(size_t)(q0 + qi) * 512 + h * 32];
#pragma unroll
            for (int d4 = 0; d4 < 8; d4++) {
                float4 tq = *(const float4*)(qp + d4 * 4);
                qreg[d4 * 4] = tq.x; qreg[d4 * 4 + 1] = tq.y;
                qreg[d4 * 4 + 2] = tq.z; qreg[d4 * 4 + 3] = tq.w;
            }
        }
        __syncthreads();
        const float scale = 0.17677669529663687f;  // 1/sqrt(32)
#pragma unroll
        for (int t2 = 0; t2 < 8; t2++) {
            int kk = kg + t2 * 16;
            if (kk < W) {
                float acc = 0.0f;
#pragma unroll
                for (int d4 = 0; d4 < 8; d4++) {
                    float4 kv = *(const float4*)&ks[kk * 36 + d4 * 4];
                    acc = fmaf(qreg[d4 * 4 + 0], kv.x, acc);
                    acc = fmaf(qreg[d4 * 4 + 1], kv.y, acc);
                    acc = fmaf(qreg[d4 * 4 + 2], kv.z, acc);
                    acc = fmaf(qreg[d4 * 4 + 3], kv.w, acc);
                }
                ps[qi * PSS + kk] = fmaf(acc, scale, ps[qi * PSS + kk]);
            }
        }
        __syncthreads();
        {
            int row = tid >> 4, sub = tid & 15;
            float m = -3.0e38f;
            for (int kk = sub; kk < W; kk += 16) m = fmaxf(m, ps[row * PSS + kk]);
#pragma unroll
            for (int s2 = 1; s2 < 16; s2 <<= 1) m = fmaxf(m, __shfl_xor(m, s2));
            float ssum = 0.0f;
            for (int kk = sub; kk < W; kk += 16) {
                float e = expf(ps[row * PSS + kk] - m);
                ps[row * PSS + kk] = e; ssum += e;
            }
#pragma unroll
            for (int s2 = 1; s2 < 16; s2 <<= 1) ssum += __shfl_xor(ssum, s2);
            float rinv = 1.0f / ssum;
            for (int kk = sub; kk < W; kk += 16) ps[row * PSS + kk] *= rinv;
        }
        __syncthreads();
        {
            int dg = tid >> 4, d0 = dg * 2;
            float o0 = 0.0f, o1 = 0.0f, o0b = 0.0f, o1b = 0.0f;
            for (int kk = 0; kk + 1 < W; kk += 2) {
                float p0 = ps[qi * PSS + kk], p1 = ps[qi * PSS + kk + 1];
                float2 va = *(const float2*)&vs[kk * 36 + d0];
                float2 vb = *(const float2*)&vs[(kk + 1) * 36 + d0];
                o0  = fmaf(p0, va.x, o0);  o1  = fmaf(p0, va.y, o1);
                o0b = fmaf(p1, vb.x, o0b); o1b = fmaf(p1, vb.y, o1b);
            }
            if (W & 1) {
                float p0 = ps[qi * PSS + W - 1];
                float2 va = *(const float2*)&vs[(W - 1) * 36 + d0];
                o0 = fmaf(p0, va.x, o0); o1 = fmaf(p0, va.y, o1);
            }
            o0 += o0b; o1 += o1b;
            float2 g2 = *(const float2*)&P.qkvg[(size_t)(q0 + qi) * 512 + 384 + h * 32 + d0];
            // g-gated head output -> LDS (ks region is dead after QK^T)
            ks[qi * 33 + d0]     = o0 * sig(g2.x);
            ks[qi * 33 + d0 + 1] = o1 * sig(g2.y);
        }
        __syncthreads();
        // per-head wo partial: bout4[h][q0+r][c] = sum_d o_s[r][d] * wo[h*32+d][c]
        {
            int r = tid >> 4, ci = tid & 15;
            int c0 = ci * 8;
            const float* o_s = ks;
            const float* wop = P.wo + (size_t)i * 16384 + (size_t)(h * 32) * 128 + c0;
            float acc[8] = {};
#pragma unroll 4
            for (int d = 0; d < 32; d++) {
                float a = o_s[r * 33 + d];
                float4 w0 = *(const float4*)(wop + (size_t)d * 128);
                float4 w1 = *(const float4*)(wop + (size_t)d * 128 + 4);
                acc[0] = fmaf(a, w0.x, acc[0]); acc[1] = fmaf(a, w0.y, acc[1]);
                acc[2] = fmaf(a, w0.z, acc[2]); acc[3] = fmaf(a, w0.w, acc[3]);
                acc[4] = fmaf(a, w1.x, acc[4]); acc[5] = fmaf(a, w1.y, acc[5]);
                acc[6] = fmaf(a, w1.z, acc[6]); acc[7] = fmaf(a, w1.w, acc[7]);
            }
            float* dst = P.bout4 + (size_t)h * NC + (size_t)(q0 + r) * 128 + c0;
            *(float4*)dst       = make_float4(acc[0], acc[1], acc[2], acc[3]);
            *(float4*)(dst + 4) = make_float4(acc[4], acc[5], acc[6], acc[7]);
        }
    } else {
        // tpart = sig(sg2)·(ffb @ ff3): 384 blocks = 8 XCD x 24 tiles(16r) x 2 col-halves(64)
        float* smC = sm;   // [16][260]
        int b2 = bid - 768;
        int x8 = b2 & 7, rest = b2 >> 3;    // 0..47
        int tl = rest >> 1, chalf = rest & 1;
        int row0 = x8 * 384 + tl * 16;
#pragma unroll
        for (int it = 0; it < 4; it++) {
            int fo = (tid + it * 256) * 4, r = fo >> 8, c = fo & 255;
            *(float4*)&smC[r * 260 + c] = *(const float4*)&P.ffb[(size_t)(row0 + r) * 256 + c];
        }
        __syncthreads();
        int r = tid >> 4, c = chalf * 64 + (tid & 15) * 4;
        const float* f3_p = P.ff3 + (size_t)i * 32768 + c;
        float acc[4] = {};
#pragma unroll 8
        for (int k = 0; k < 256; k++) {
            float4 w4 = *(const float4*)(f3_p + (size_t)k * 128);
            float a = smC[r * 260 + k];
            acc[0] = fmaf(a, w4.x, acc[0]);
            acc[1] = fmaf(a, w4.y, acc[1]);
            acc[2] = fmaf(a, w4.z, acc[2]);
            acc[3] = fmaf(a, w4.w, acc[3]);
        }
        int row = row0 + r;
        float4 g5 = *(const float4*)&P.G[(size_t)(5 * NBLK + i) * NC + (size_t)row * 128 + c];
        *(float4*)&P.tpart[(size_t)row * 128 + c] =
            make_float4(g5.x * acc[0], g5.y * acc[1], g5.z * acc[2], g5.w * acc[3]);
    }
}

// ================= kC: final combine out = G4·Σ bout4 + tpart (layer NBLK-1) ==============
__global__ __launch_bounds__(256) void kC_out(Params P)
{
    const size_t NC = (size_t)NTOK * 128;
    int idx = blockIdx.x * 256 + threadIdx.x;
    int r = idx >> 5, cq = (idx & 31) * 4;
    size_t off = (size_t)r * 128 + cq;
    float4 p0 = *(const float4*)&P.bout4[off];
    float4 p1 = *(const float4*)&P.bout4[NC + off];
    float4 p2 = *(const float4*)&P.bout4[2 * NC + off];
    float4 p3 = *(const float4*)&P.bout4[3 * NC + off];
    float4 tp = *(const float4*)&P.tpart[off];
    float4 gs = *(const float4*)&P.G[(size_t)(4 * NBLK + (NBLK - 1)) * NC + off];
    float4 o;
    o.x = fmaf(gs.x, p0.x + p1.x + p2.x + p3.x, tp.x);
    o.y = fmaf(gs.y, p0.y + p1.y + p2.y + p3.y, tp.y);
    o.z = fmaf(gs.z, p0.z + p1.z + p2.z + p3.z, tp.z);
    o.w = fmaf(gs.w, p0.w + p1.w + p2.w + p3.w, tp.w);
    *(float4*)&P.out[off] = o;
}

extern "C" void kernel_launch(void* const* d_in, const int* in_sizes, int n_in,
                              void* d_out, int out_size, void* d_ws, size_t ws_size,
                              hipStream_t stream)
{
    Params P;
    P.ql       = (const float*)d_in[0];
    P.cl       = (const float*)d_in[1];
    P.plm      = (const float*)d_in[2];
    P.ada_g_w  = (const float*)d_in[3];
    P.ada_g_b  = (const float*)d_in[4];
    P.ada_b_w  = (const float*)d_in[5];
    P.wq       = (const float*)d_in[6];
    P.bq       = (const float*)d_in[7];
    P.wk       = (const float*)d_in[8];
    P.wv       = (const float*)d_in[9];
    P.z_ln_g   = (const float*)d_in[10];
    P.z_ln_b   = (const float*)d_in[11];
    P.wz       = (const float*)d_in[12];
    P.wg       = (const float*)d_in[13];
    P.wo       = (const float*)d_in[14];
    P.sg_w     = (const float*)d_in[15];
    P.sg_b     = (const float*)d_in[16];
    P.ada2_g_w = (const float*)d_in[17];
    P.ada2_g_b = (const float*)d_in[18];
    P.ada2_b_w = (const float*)d_in[19];
    P.ff1      = (const float*)d_in[20];
    P.ff2      = (const float*)d_in[21];
    P.ff3      = (const float*)d_in[22];
    P.sg2_w    = (const float*)d_in[23];
    P.sg2_b    = (const float*)d_in[24];

    float* ws = (float*)d_ws;
    const size_t NC = (size_t)NTOK * 128;
    P.qkvg  = ws;             // N x 512
    P.ffb   = ws + 4 * NC;    // N x 256
    P.zb    = ws + 6 * NC;    // 3 x 4 x N x 128
    P.G     = ws + 18 * NC;   // 18 x N x 128 (6 kinds x 3 layers)
    P.bout4 = ws + 36 * NC;   // 4 x N x 128 (per-head wo partials)
    P.tpart = ws + 40 * NC;   // N x 128
    P.out   = (float*)d_out;

    kInit<<<384, 256, 0, stream>>>(P);
    for (int i = 0; i < NBLK; i++) {
        kA_pre<<<(i == 0 ? 2304 : 576), 256, 0, stream>>>(P, i);
        kB_attn<<<1152, 256, 0, stream>>>(P, i);
    }
    kC_out<<<384, 256, 0, stream>>>(P);
}

// Round 15
// 263.901 us; speedup vs baseline: 1.3221x; 1.0473x over previous
//
#include <hip/hip_runtime.h>
#include <cmath>

#define NTOK 3072
#define NBLK 3
#define PSS 133   // ps LDS stride: %32 == 5 -> conflict-free reads

__device__ __forceinline__ float sig(float v) { return 1.0f / (1.0f + expf(-v)); }

struct Params {
    const float *ql, *cl, *plm;
    const float *ada_g_w, *ada_g_b, *ada_b_w;
    const float *wq, *bq, *wk, *wv;
    const float *z_ln_g, *z_ln_b, *wz;
    const float *wg, *wo, *sg_w, *sg_b;
    const float *ada2_g_w, *ada2_g_b, *ada2_b_w;
    const float *ff1, *ff2, *ff3, *sg2_w, *sg2_b;
    float *qkvg, *ffb, *zb, *G, *bout4, *tpart;
    float *out;
};

// 32-lane-subgroup row LN of 4 register values (cols (lane&31)*4 .. +3 of a 128-col row)
__device__ __forceinline__ float4 ln_row32(float4 v)
{
    float s = v.x + v.y + v.z + v.w;
#pragma unroll
    for (int m = 1; m < 32; m <<= 1) s += __shfl_xor(s, m);
    float mean = s * (1.0f / 128.0f);
    float d0 = v.x - mean, d1 = v.y - mean, d2 = v.z - mean, d3 = v.w - mean;
    float var = d0 * d0 + d1 * d1 + d2 * d2 + d3 * d3;
#pragma unroll
    for (int m = 1; m < 32; m <<= 1) var += __shfl_xor(var, m);
    float rs = 1.0f / sqrtf(var * (1.0f / 128.0f) + 1e-5f);
    return make_float4(d0 * rs, d1 * rs, d2 * rs, d3 * rs);
}

// ================= k0: all conditioning GEMMs (18 units) + pair bias zb =================
// blocks [0,1728): gemm: 8 XCD x 12 tiles(32 rows) x 18 units (6 kinds x 3 layers)
// blocks [1728,2112): zb: 8 XCD x 12 j x 4 kk-chunks
__global__ __launch_bounds__(256) void k0_cond(Params P)
{
    int tid = threadIdx.x, bid = blockIdx.x;
    const size_t NC = (size_t)NTOK * 128;
    if (bid < 1728) {
        __shared__ __align__(16) float smA[32 * 132];
        int x8 = bid & 7, rest = bid >> 3;          // rest 0..215
        int tl = rest % 12, unit = rest / 12;       // unit 0..17
        int kind = unit % 6, i = unit / 6;
        int row0 = (x8 * 12 + tl) * 32;
#pragma unroll
        for (int it = 0; it < 4; it++) {
            int fo = (tid + it * 256) * 4, r = fo >> 7, c = fo & 127;
            *(float4*)&smA[r * 132 + c] = *(const float4*)&P.cl[(size_t)(row0 + r) * 128 + c];
        }
        __syncthreads();
        int hw = tid >> 5, cq = (tid & 31) * 4;
#pragma unroll
        for (int rr = 0; rr < 4; rr++) {
            int r = hw * 4 + rr;
            float4 n = ln_row32(*(float4*)&smA[r * 132 + cq]);
            *(float4*)&smA[r * 132 + cq] = n;
        }
        __syncthreads();
        const float* W; const float* bias = nullptr; bool dosig = false;
        switch (kind) {
            case 0:  W = P.ada_g_w  + (size_t)i * 16384; bias = P.ada_g_b  + i * 128; dosig = true; break;
            case 1:  W = P.ada_b_w  + (size_t)i * 16384; break;
            case 2:  W = P.ada2_g_w + (size_t)i * 16384; bias = P.ada2_g_b + i * 128; dosig = true; break;
            case 3:  W = P.ada2_b_w + (size_t)i * 16384; break;
            case 4:  W = P.sg_w     + (size_t)i * 16384; bias = P.sg_b     + i * 128; dosig = true; break;
            default: W = P.sg2_w    + (size_t)i * 16384; bias = P.sg2_b    + i * 128; dosig = true; break;
        }
        W += cq;
        float acc[4][4] = {};
#pragma unroll 8
        for (int k = 0; k < 128; k++) {
            float4 w4 = *(const float4*)(W + (size_t)k * 128);
#pragma unroll
            for (int rr = 0; rr < 4; rr++) {
                float a = smA[(hw * 4 + rr) * 132 + k];
                acc[rr][0] = fmaf(a, w4.x, acc[rr][0]);
                acc[rr][1] = fmaf(a, w4.y, acc[rr][1]);
                acc[rr][2] = fmaf(a, w4.z, acc[rr][2]);
                acc[rr][3] = fmaf(a, w4.w, acc[rr][3]);
            }
        }
        float4 b4 = bias ? *(const float4*)&bias[cq] : make_float4(0, 0, 0, 0);
        float* dst = P.G + (size_t)(kind * NBLK + i) * NC;
#pragma unroll
        for (int rr = 0; rr < 4; rr++) {
            float4 o = make_float4(acc[rr][0] + b4.x, acc[rr][1] + b4.y,
                                   acc[rr][2] + b4.z, acc[rr][3] + b4.w);
            if (dosig) { o.x = sig(o.x); o.y = sig(o.y); o.z = sig(o.z); o.w = sig(o.w); }
            *(float4*)&dst[(size_t)(row0 + hw * 4 + rr) * 128 + cq] = o;
        }
    } else {
        __shared__ __align__(16) float wzg[204];
        int b2 = bid - 1728;
        int x8 = b2 & 7, rest = b2 >> 3;    // rest 0..47
        int jl = rest >> 2, kkc = rest & 3;
        int j = x8 * 12 + jl;
        if (tid < 192) {
            int i3 = tid >> 6, rem = tid & 63, c = rem >> 2, h = rem & 3;
            wzg[(i3 * 16 + c) * 4 + h] = P.z_ln_g[i3 * 16 + c] * P.wz[(i3 * 16 + c) * 4 + h];
        }
        if (tid < 12) {
            int i3 = tid >> 2, h = tid & 3;
            float s = 0.0f;
            for (int c = 0; c < 16; c++) s += P.z_ln_b[i3 * 16 + c] * P.wz[(i3 * 16 + c) * 4 + h];
            wzg[192 + tid] = s;
        }
        __syncthreads();
        int kstart = max(0, j * 32 - 48);
        int W = min(NTOK, j * 32 + 80) - kstart;
#pragma unroll
        for (int it = 0; it < 4; it++) {
            int idx = tid + it * 256;
            int qi = idx >> 5, kk = kkc * 32 + (idx & 31);
            if (kk >= W) continue;
            int q = j * 32 + qi;
            const float* src = P.plm + ((size_t)q * NTOK + (size_t)(kstart + kk)) * 16;
            float xv[16];
            *(float4*)(xv + 0)  = *(const float4*)(src + 0);
            *(float4*)(xv + 4)  = *(const float4*)(src + 4);
            *(float4*)(xv + 8)  = *(const float4*)(src + 8);
            *(float4*)(xv + 12) = *(const float4*)(src + 12);
            float s = 0.0f;
#pragma unroll
            for (int c = 0; c < 16; c++) s += xv[c];
            float mean = s * (1.0f / 16.0f);
            float var = 0.0f;
#pragma unroll
            for (int c = 0; c < 16; c++) { float d = xv[c] - mean; var += d * d; }
            float rs = 1.0f / sqrtf(var * (1.0f / 16.0f) + 1e-5f);
#pragma unroll
            for (int c = 0; c < 16; c++) xv[c] = (xv[c] - mean) * rs;
#pragma unroll
            for (int i3 = 0; i3 < NBLK; i3++) {
#pragma unroll
                for (int h = 0; h < 4; h++) {
                    float o = wzg[192 + i3 * 4 + h];
#pragma unroll
                    for (int c = 0; c < 16; c++) o = fmaf(xv[c], wzg[(i3 * 16 + c) * 4 + h], o);
                    P.zb[((size_t)(i3 * 4 + h) * NTOK + q) * 128 + kk] = o;
                }
            }
        }
    }
}

// ================= kA: x|y elementwise + single projection GEMM =================
// grid 576 = 8 XCD x 12 tiles(32 rows) x 6 units {q,k,v,g, ff-lo, ff-hi}
// i>0: a_prev reconstructed in-register: G4·(Σ_h bout4) + tpart
__global__ __launch_bounds__(256) void kA_pre(Params P, int i)
{
    __shared__ __align__(16) float smX[32 * 132];
    const size_t NC = (size_t)NTOK * 128;
    int tid = threadIdx.x, bid = blockIdx.x;
    int x8 = bid & 7, rest = bid >> 3;      // 0..71
    int tl = rest % 12, u = rest / 12;      // u 0..5
    int row0 = (x8 * 12 + tl) * 32;
    int hw = tid >> 5, cq = (tid & 31) * 4;
    const float* Gg = P.G + (size_t)(((u < 4 ? 0 : 2) * NBLK) + i) * NC;
    const float* Gb = P.G + (size_t)(((u < 4 ? 1 : 3) * NBLK) + i) * NC;
    const float* G4p = P.G + (size_t)(4 * NBLK + (i > 0 ? i - 1 : 0)) * NC;
#pragma unroll
    for (int rr = 0; rr < 4; rr++) {
        int r = row0 + hw * 4 + rr;
        size_t off = (size_t)r * 128 + cq;
        float4 a4;
        if (i == 0) {
            a4 = *(const float4*)&P.ql[off];
        } else {
            float4 p0 = *(const float4*)&P.bout4[off];
            float4 p1 = *(const float4*)&P.bout4[NC + off];
            float4 p2 = *(const float4*)&P.bout4[2 * NC + off];
            float4 p3 = *(const float4*)&P.bout4[3 * NC + off];
            float4 tp = *(const float4*)&P.tpart[off];
            float4 gs = *(const float4*)&G4p[off];
            a4.x = fmaf(gs.x, p0.x + p1.x + p2.x + p3.x, tp.x);
            a4.y = fmaf(gs.y, p0.y + p1.y + p2.y + p3.y, tp.y);
            a4.z = fmaf(gs.z, p0.z + p1.z + p2.z + p3.z, tp.z);
            a4.w = fmaf(gs.w, p0.w + p1.w + p2.w + p3.w, tp.w);
        }
        float4 ln4 = ln_row32(a4);
        float4 g4 = *(const float4*)&Gg[off];
        float4 b4 = *(const float4*)&Gb[off];
        float4 x4;
        x4.x = fmaf(g4.x, ln4.x, b4.x);
        x4.y = fmaf(g4.y, ln4.y, b4.y);
        x4.z = fmaf(g4.z, ln4.z, b4.z);
        x4.w = fmaf(g4.w, ln4.w, b4.w);
        *(float4*)&smX[(hw * 4 + rr) * 132 + cq] = x4;
    }
    __syncthreads();
    if (u < 4) {
        const float* W = (u == 0 ? P.wq : u == 1 ? P.wk : u == 2 ? P.wv : P.wg)
                         + (size_t)i * 16384 + cq;
        float acc[4][4] = {};
#pragma unroll 8
        for (int k = 0; k < 128; k++) {
            float4 w4 = *(const float4*)(W + (size_t)k * 128);
#pragma unroll
            for (int rr = 0; rr < 4; rr++) {
                float a = smX[(hw * 4 + rr) * 132 + k];
                acc[rr][0] = fmaf(a, w4.x, acc[rr][0]);
                acc[rr][1] = fmaf(a, w4.y, acc[rr][1]);
                acc[rr][2] = fmaf(a, w4.z, acc[rr][2]);
                acc[rr][3] = fmaf(a, w4.w, acc[rr][3]);
            }
        }
        float4 b4 = (u == 0) ? *(const float4*)&P.bq[(size_t)i * 128 + cq]
                             : make_float4(0, 0, 0, 0);
#pragma unroll
        for (int rr = 0; rr < 4; rr++) {
            int r = row0 + hw * 4 + rr;
            *(float4*)&P.qkvg[(size_t)r * 512 + u * 128 + cq] =
                make_float4(acc[rr][0] + b4.x, acc[rr][1] + b4.y,
                            acc[rr][2] + b4.z, acc[rr][3] + b4.w);
        }
    } else {
        int ch = (u - 4) * 128;
        const float* W1 = P.ff1 + (size_t)i * 32768 + ch + cq;
        const float* W2 = P.ff2 + (size_t)i * 32768 + ch + cq;
        float a1[4][4] = {}, a2[4][4] = {};
#pragma unroll 4
        for (int k = 0; k < 128; k++) {
            float4 w14 = *(const float4*)(W1 + (size_t)k * 256);
            float4 w24 = *(const float4*)(W2 + (size_t)k * 256);
#pragma unroll
            for (int rr = 0; rr < 4; rr++) {
                float a = smX[(hw * 4 + rr) * 132 + k];
                a1[rr][0] = fmaf(a, w14.x, a1[rr][0]);
                a1[rr][1] = fmaf(a, w14.y, a1[rr][1]);
                a1[rr][2] = fmaf(a, w14.z, a1[rr][2]);
                a1[rr][3] = fmaf(a, w14.w, a1[rr][3]);
                a2[rr][0] = fmaf(a, w24.x, a2[rr][0]);
                a2[rr][1] = fmaf(a, w24.y, a2[rr][1]);
                a2[rr][2] = fmaf(a, w24.z, a2[rr][2]);
                a2[rr][3] = fmaf(a, w24.w, a2[rr][3]);
            }
        }
#pragma unroll
        for (int rr = 0; rr < 4; rr++) {
            int r = row0 + hw * 4 + rr;
            float4 o;
            o.x = a1[rr][0] * sig(a1[rr][0]) * a2[rr][0];
            o.y = a1[rr][1] * sig(a1[rr][1]) * a2[rr][1];
            o.z = a1[rr][2] * sig(a1[rr][2]) * a2[rr][2];
            o.w = a1[rr][3] * sig(a1[rr][3]) * a2[rr][3];
            *(float4*)&P.ffb[(size_t)r * 256 + ch + cq] = o;
        }
    }
}

// ================= kB: attention + per-head wo partial (blocks 0..767)
//                      + tpart = sig(sg2)·(ffb@ff3)   (blocks 768..1151) ==================
__global__ __launch_bounds__(256) void kB_attn(Params P, int i)
{
    __shared__ __align__(16) float sm[11344];   // ks[4608] | vs[4608] | ps[16*133]; union tpart [16*260]
    const size_t NC = (size_t)NTOK * 128;
    int tid = threadIdx.x, bid = blockIdx.x;
    if (bid < 768) {
        float* ks = sm;             // [128][36]; reused as o_s[16][33] after QK^T/PV
        float* vs = sm + 4608;      // [128][36]
        float* ps = sm + 9216;      // [16][PSS]
        int x8 = bid & 7, g = bid >> 3;            // 0..95
        int jl = g >> 3, rem = g & 7;
        int h = rem >> 1, qh = rem & 1;
        int jglob = x8 * 12 + jl;
        int q0 = jglob * 32 + qh * 16;
        int kstart = max(0, jglob * 32 - 48);
        int W = min(NTOK, jglob * 32 + 80) - kstart;
        for (int idx = tid; idx < W * 8; idx += 256) {
            int kk = idx >> 3, d = (idx & 7) * 4;
            const float* base = &P.qkvg[(size_t)(kstart + kk) * 512 + 128 + h * 32 + d];
            float4 tK = *(const float4*)base;
            float4 tV = *(const float4*)(base + 128);
            *(float4*)&ks[kk * 36 + d] = tK;
            *(float4*)&vs[kk * 36 + d] = tV;
        }
        const float* zbase = &P.zb[((size_t)(i * 4 + h) * NTOK + q0) * 128];
#pragma unroll
        for (int it = 0; it < 2; it++) {
            int idx = tid + it * 256;
            int r = idx >> 5, c4 = (idx & 31) * 4;
            float4 z4 = *(const float4*)&zbase[(size_t)r * 128 + c4];
            ps[r * PSS + c4]     = z4.x;
            ps[r * PSS + c4 + 1] = z4.y;
            ps[r * PSS + c4 + 2] = z4.z;
            ps[r * PSS + c4 + 3] = z4.w;
        }
        int qi = tid & 15, kg = tid >> 4;
        float qreg[32];
        {
            const float* qp = &P.qkvg[(size_t)(q0 + qi) * 512 + h * 32];
#pragma unroll
            for (int d4 = 0; d4 < 8; d4++) {
                float4 tq = *(const float4*)(qp + d4 * 4);
                qreg[d4 * 4] = tq.x; qreg[d4 * 4 + 1] = tq.y;
                qreg[d4 * 4 + 2] = tq.z; qreg[d4 * 4 + 3] = tq.w;
            }
        }
        __syncthreads();
        const float scale = 0.17677669529663687f;  // 1/sqrt(32)
#pragma unroll
        for (int t2 = 0; t2 < 8; t2++) {
            int kk = kg + t2 * 16;
            if (kk < W) {
                float acc = 0.0f;
#pragma unroll
                for (int d4 = 0; d4 < 8; d4++) {
                    float4 kv = *(const float4*)&ks[kk * 36 + d4 * 4];
                    acc = fmaf(qreg[d4 * 4 + 0], kv.x, acc);
                    acc = fmaf(qreg[d4 * 4 + 1], kv.y, acc);
                    acc = fmaf(qreg[d4 * 4 + 2], kv.z, acc);
                    acc = fmaf(qreg[d4 * 4 + 3], kv.w, acc);
                }
                ps[qi * PSS + kk] = fmaf(acc, scale, ps[qi * PSS + kk]);
            }
        }
        __syncthreads();
        {
            int row = tid >> 4, sub = tid & 15;
            float m = -3.0e38f;
            for (int kk = sub; kk < W; kk += 16) m = fmaxf(m, ps[row * PSS + kk]);
#pragma unroll
            for (int s2 = 1; s2 < 16; s2 <<= 1) m = fmaxf(m, __shfl_xor(m, s2));
            float ssum = 0.0f;
            for (int kk = sub; kk < W; kk += 16) {
                float e = expf(ps[row * PSS + kk] - m);
                ps[row * PSS + kk] = e; ssum += e;
            }
#pragma unroll
            for (int s2 = 1; s2 < 16; s2 <<= 1) ssum += __shfl_xor(ssum, s2);
            float rinv = 1.0f / ssum;
            for (int kk = sub; kk < W; kk += 16) ps[row * PSS + kk] *= rinv;
        }
        __syncthreads();
        {
            int dg = tid >> 4, d0 = dg * 2;
            float o0 = 0.0f, o1 = 0.0f, o0b = 0.0f, o1b = 0.0f;
            for (int kk = 0; kk + 1 < W; kk += 2) {
                float p0 = ps[qi * PSS + kk], p1 = ps[qi * PSS + kk + 1];
                float2 va = *(const float2*)&vs[kk * 36 + d0];
                float2 vb = *(const float2*)&vs[(kk + 1) * 36 + d0];
                o0  = fmaf(p0, va.x, o0);  o1  = fmaf(p0, va.y, o1);
                o0b = fmaf(p1, vb.x, o0b); o1b = fmaf(p1, vb.y, o1b);
            }
            if (W & 1) {
                float p0 = ps[qi * PSS + W - 1];
                float2 va = *(const float2*)&vs[(W - 1) * 36 + d0];
                o0 = fmaf(p0, va.x, o0); o1 = fmaf(p0, va.y, o1);
            }
            o0 += o0b; o1 += o1b;
            float2 g2 = *(const float2*)&P.qkvg[(size_t)(q0 + qi) * 512 + 384 + h * 32 + d0];
            // g-gated head output -> LDS (ks region is dead after QK^T)
            ks[qi * 33 + d0]     = o0 * sig(g2.x);
            ks[qi * 33 + d0 + 1] = o1 * sig(g2.y);
        }
        __syncthreads();
        // per-head wo partial: bout4[h][q0+r][c] = sum_d o_s[r][d] * wo[h*32+d][c]
        {
            int r = tid >> 4, ci = tid & 15;
            int c0 = ci * 8;
            const float* o_s = ks;
            const float* wop = P.wo + (size_t)i * 16384 + (size_t)(h * 32) * 128 + c0;
            float acc[8] = {};
#pragma unroll 4
            for (int d = 0; d < 32; d++) {
                float a = o_s[r * 33 + d];
                float4 w0 = *(const float4*)(wop + (size_t)d * 128);
                float4 w1 = *(const float4*)(wop + (size_t)d * 128 + 4);
                acc[0] = fmaf(a, w0.x, acc[0]); acc[1] = fmaf(a, w0.y, acc[1]);
                acc[2] = fmaf(a, w0.z, acc[2]); acc[3] = fmaf(a, w0.w, acc[3]);
                acc[4] = fmaf(a, w1.x, acc[4]); acc[5] = fmaf(a, w1.y, acc[5]);
                acc[6] = fmaf(a, w1.z, acc[6]); acc[7] = fmaf(a, w1.w, acc[7]);
            }
            float* dst = P.bout4 + (size_t)h * NC + (size_t)(q0 + r) * 128 + c0;
            *(float4*)dst       = make_float4(acc[0], acc[1], acc[2], acc[3]);
            *(float4*)(dst + 4) = make_float4(acc[4], acc[5], acc[6], acc[7]);
        }
    } else {
        // tpart = sig(sg2)·(ffb @ ff3): 384 blocks = 8 XCD x 24 tiles(16r) x 2 col-halves(64)
        float* smC = sm;   // [16][260]
        int b2 = bid - 768;
        int x8 = b2 & 7, rest = b2 >> 3;    // 0..47
        int tl = rest >> 1, chalf = rest & 1;
        int row0 = x8 * 384 + tl * 16;
#pragma unroll
        for (int it = 0; it < 4; it++) {
            int fo = (tid + it * 256) * 4, r = fo >> 8, c = fo & 255;
            *(float4*)&smC[r * 260 + c] = *(const float4*)&P.ffb[(size_t)(row0 + r) * 256 + c];
        }
        __syncthreads();
        int r = tid >> 4, c = chalf * 64 + (tid & 15) * 4;
        const float* f3_p = P.ff3 + (size_t)i * 32768 + c;
        float acc[4] = {};
#pragma unroll 8
        for (int k = 0; k < 256; k++) {
            float4 w4 = *(const float4*)(f3_p + (size_t)k * 128);
            float a = smC[r * 260 + k];
            acc[0] = fmaf(a, w4.x, acc[0]);
            acc[1] = fmaf(a, w4.y, acc[1]);
            acc[2] = fmaf(a, w4.z, acc[2]);
            acc[3] = fmaf(a, w4.w, acc[3]);
        }
        int row = row0 + r;
        float4 g5 = *(const float4*)&P.G[(size_t)(5 * NBLK + i) * NC + (size_t)row * 128 + c];
        *(float4*)&P.tpart[(size_t)row * 128 + c] =
            make_float4(g5.x * acc[0], g5.y * acc[1], g5.z * acc[2], g5.w * acc[3]);
    }
}

// ================= kC: final combine out = G4·Σ bout4 + tpart (layer NBLK-1) ==============
__global__ __launch_bounds__(256) void kC_out(Params P)
{
    const size_t NC = (size_t)NTOK * 128;
    int idx = blockIdx.x * 256 + threadIdx.x;
    int r = idx >> 5, cq = (idx & 31) * 4;
    size_t off = (size_t)r * 128 + cq;
    float4 p0 = *(const float4*)&P.bout4[off];
    float4 p1 = *(const float4*)&P.bout4[NC + off];
    float4 p2 = *(const float4*)&P.bout4[2 * NC + off];
    float4 p3 = *(const float4*)&P.bout4[3 * NC + off];
    float4 tp = *(const float4*)&P.tpart[off];
    float4 gs = *(const float4*)&P.G[(size_t)(4 * NBLK + (NBLK - 1)) * NC + off];
    float4 o;
    o.x = fmaf(gs.x, p0.x + p1.x + p2.x + p3.x, tp.x);
    o.y = fmaf(gs.y, p0.y + p1.y + p2.y + p3.y, tp.y);
    o.z = fmaf(gs.z, p0.z + p1.z + p2.z + p3.z, tp.z);
    o.w = fmaf(gs.w, p0.w + p1.w + p2.w + p3.w, tp.w);
    *(float4*)&P.out[off] = o;
}

extern "C" void kernel_launch(void* const* d_in, const int* in_sizes, int n_in,
                              void* d_out, int out_size, void* d_ws, size_t ws_size,
                              hipStream_t stream)
{
    Params P;
    P.ql       = (const float*)d_in[0];
    P.cl       = (const float*)d_in[1];
    P.plm      = (const float*)d_in[2];
    P.ada_g_w  = (const float*)d_in[3];
    P.ada_g_b  = (const float*)d_in[4];
    P.ada_b_w  = (const float*)d_in[5];
    P.wq       = (const float*)d_in[6];
    P.bq       = (const float*)d_in[7];
    P.wk       = (const float*)d_in[8];
    P.wv       = (const float*)d_in[9];
    P.z_ln_g   = (const float*)d_in[10];
    P.z_ln_b   = (const float*)d_in[11];
    P.wz       = (const float*)d_in[12];
    P.wg       = (const float*)d_in[13];
    P.wo       = (const float*)d_in[14];
    P.sg_w     = (const float*)d_in[15];
    P.sg_b     = (const float*)d_in[16];
    P.ada2_g_w = (const float*)d_in[17];
    P.ada2_g_b = (const float*)d_in[18];
    P.ada2_b_w = (const float*)d_in[19];
    P.ff1      = (const float*)d_in[20];
    P.ff2      = (const float*)d_in[21];
    P.ff3      = (const float*)d_in[22];
    P.sg2_w    = (const float*)d_in[23];
    P.sg2_b    = (const float*)d_in[24];

    float* ws = (float*)d_ws;
    const size_t NC = (size_t)NTOK * 128;
    P.qkvg  = ws;             // N x 512
    P.ffb   = ws + 4 * NC;    // N x 256
    P.zb    = ws + 6 * NC;    // 3 x 4 x N x 128
    P.G     = ws + 18 * NC;   // 18 x N x 128 (6 kinds x 3 layers)
    P.bout4 = ws + 36 * NC;   // 4 x N x 128 (per-head wo partials)
    P.tpart = ws + 40 * NC;   // N x 128
    P.out   = (float*)d_out;

    k0_cond<<<2112, 256, 0, stream>>>(P);
    for (int i = 0; i < NBLK; i++) {
        kA_pre<<<576, 256, 0, stream>>>(P, i);
        kB_attn<<<1152, 256, 0, stream>>>(P, i);
    }
    kC_out<<<384, 256, 0, stream>>>(P);
}